// Round 10
// baseline (3016.955 us; speedup 1.0000x reference)
//
#include <hip/hip_runtime.h>
#include <hip/hip_cooperative_groups.h>
#include <math.h>

namespace cg = cooperative_groups;

// Problem constants
#define B_   32
#define T_   256
#define DV_  1024
#define DJ_  512
#define L_   20
#define T0_  127
#define T1_  62
#define T2_  30
#define TP_  219          // 127+62+30
#define LAM_ 4.0f
#define MARGIN_ 0.1f
#define NB_  1024         // persistent grid blocks (4/CU x 256 CU)
#define SHBYTES 25600     // 24KB gemm dbuf + 1KB wred; >= all other stages

typedef __attribute__((ext_vector_type(8))) short short8;
typedef __attribute__((ext_vector_type(4))) float f32x4;

static __device__ __forceinline__ unsigned short f2bf(float f) {
  union { float f; unsigned u; } v; v.f = f;
  unsigned r = v.u + 0x7fff + ((v.u >> 16) & 1);   // round-to-nearest-even
  return (unsigned short)(r >> 16);
}

struct ushort4_t { unsigned short x, y, z, w; };

#define GLOAD_LDS16(gp, lp)                                                      \
  __builtin_amdgcn_global_load_lds(                                              \
      (const __attribute__((address_space(1))) void*)(gp),                       \
      (__attribute__((address_space(3))) void*)(lp), 16, 0, 0)

// ---------------------------------------------------------------------------
struct MegaParams {
  const float *video, *words, *wmask;
  const float *c0w, *c0b, *c1w, *c1b, *c2w, *c2b, *pww, *pwb;
  float* out;
  unsigned short *W0, *W1, *W2, *Wp, *vbf, *vcb, *v2bf, *wbnb;
  float *Amat, *Pbuf, *v2, *v2part, *v2ms, *vpart, *vms, *wpart, *wms,
        *G, *vn, *scores;
};

// ---------------------------------------------------------------------------
// BatchNorm stats bodies (deterministic two-stage).
// ---------------------------------------------------------------------------
__device__ __forceinline__ void stats1_body(const float* __restrict__ x,
                                            float* __restrict__ part,
                                            int C, int rows, int rpg, int cpgShift,
                                            int bid, int tid) {
  int cpg  = 1 << cpgShift;                 // C/4
  int c4   = tid & (cpg - 1);
  int rsub = tid >> cpgShift;
  int nsub = 256 >> cpgShift;
  int r0 = bid * rpg + rsub;
  int r1 = min(bid * rpg + rpg, rows);
  float4 s = {0.f,0.f,0.f,0.f}, q = {0.f,0.f,0.f,0.f};
  for (int r = r0; r < r1; r += nsub) {
    float4 v = *reinterpret_cast<const float4*>(&x[(size_t)r * C + c4 * 4]);
    s.x += v.x; s.y += v.y; s.z += v.z; s.w += v.w;
    q.x += v.x*v.x; q.y += v.y*v.y; q.z += v.z*v.z; q.w += v.w*v.w;
  }
  float* ps = part + ((size_t)bid * nsub + rsub) * 2 * C;
  reinterpret_cast<float4*>(ps)[c4] = s;
  reinterpret_cast<float4*>(ps + C)[c4] = q;
}

__device__ __forceinline__ void stats2_body(const float* __restrict__ part,
                                            float* __restrict__ ms,
                                            int C, int ng, float inv_n,
                                            int bid, int tid,
                                            float4* sS, float4* sQ) {
  int c4l = tid & 31;
  int gs  = tid >> 5;
  int c4  = bid * 32 + c4l;                 // float4 channel index
  float4 s = {0.f,0.f,0.f,0.f}, q = {0.f,0.f,0.f,0.f};
  for (int g = gs; g < ng; g += 8) {
    const float4* ps = reinterpret_cast<const float4*>(part + (size_t)g * 2 * C);
    float4 a = ps[c4];
    float4 b = ps[(C >> 2) + c4];
    s.x += a.x; s.y += a.y; s.z += a.z; s.w += a.w;
    q.x += b.x; q.y += b.y; q.z += b.z; q.w += b.w;
  }
  sS[gs * 33 + c4l] = s; sQ[gs * 33 + c4l] = q;
  __syncthreads();
  if (gs == 0) {
    float4 S = sS[c4l], Q = sQ[c4l];
#pragma unroll
    for (int k = 1; k < 8; ++k) {
      float4 a = sS[k * 33 + c4l], b = sQ[k * 33 + c4l];
      S.x += a.x; S.y += a.y; S.z += a.z; S.w += a.w;
      Q.x += b.x; Q.y += b.y; Q.z += b.z; Q.w += b.w;
    }
    int c = c4 * 4;
    float m0 = S.x * inv_n, m1 = S.y * inv_n, m2 = S.z * inv_n, m3 = S.w * inv_n;
    ms[c+0] = m0; ms[C+c+0] = rsqrtf(Q.x * inv_n - m0*m0 + 1e-5f);
    ms[c+1] = m1; ms[C+c+1] = rsqrtf(Q.y * inv_n - m1*m1 + 1e-5f);
    ms[c+2] = m2; ms[C+c+2] = rsqrtf(Q.z * inv_n - m2*m2 + 1e-5f);
    ms[c+3] = m3; ms[C+c+3] = rsqrtf(Q.w * inv_n - m3*m3 + 1e-5f);
  }
}

// ---------------------------------------------------------------------------
// prep: weight reorder+cast (0..4351) | video stats1 (4352..4863) | words
// stats1 (4864..4903).
// ---------------------------------------------------------------------------
__device__ __forceinline__ void prep_body(const MegaParams& P, int bid, int tid) {
  if (bid < 2048) {            // conv0: 512*1024 (co,ci) pairs
    int idx = bid * 256 + tid;
    int co = idx >> 10, ci = idx & 1023;
    float4 w = *reinterpret_cast<const float4*>(P.c0w + (size_t)idx * 4);
    unsigned short* d = P.W0 + (size_t)co * 4096 + ci;
    d[0] = f2bf(w.x); d[1024] = f2bf(w.y); d[2048] = f2bf(w.z); d[3072] = f2bf(w.w);
  } else if (bid < 3072) {     // conv1
    int idx = (bid - 2048) * 256 + tid;
    int co = idx >> 9, ci = idx & 511;
    float4 w = *reinterpret_cast<const float4*>(P.c1w + (size_t)idx * 4);
    unsigned short* d = P.W1 + (size_t)co * 2048 + ci;
    d[0] = f2bf(w.x); d[512] = f2bf(w.y); d[1024] = f2bf(w.z); d[1536] = f2bf(w.w);
  } else if (bid < 4096) {     // conv2
    int idx = (bid - 3072) * 256 + tid;
    int co = idx >> 9, ci = idx & 511;
    float4 w = *reinterpret_cast<const float4*>(P.c2w + (size_t)idx * 4);
    unsigned short* d = P.W2 + (size_t)co * 2048 + ci;
    d[0] = f2bf(w.x); d[512] = f2bf(w.y); d[1024] = f2bf(w.z); d[1536] = f2bf(w.w);
  } else if (bid < 4352) {     // pw identity cast
    int idx = (bid - 4096) * 256 + tid;
    float4 v = *reinterpret_cast<const float4*>(P.pww + (size_t)idx * 4);
    ushort4_t h = { f2bf(v.x), f2bf(v.y), f2bf(v.z), f2bf(v.w) };
    reinterpret_cast<ushort4_t*>(P.Wp)[idx] = h;
  } else if (bid < 4864) {     // video stats1
    stats1_body(P.video, P.vpart, 1024, 8192, 16, 8, bid - 4352, tid);
  } else {                     // words stats1
    stats1_body(P.words, P.wpart, 512, 640, 16, 7, bid - 4864, tid);
  }
}

__device__ __forceinline__ void stats2c_body(const MegaParams& P, int bid, int tid,
                                             char* shraw) {
  float4* sS = (float4*)shraw;
  float4* sQ = sS + 264;
  if (bid < 8) stats2_body(P.vpart, P.vms, 1024, 512, 1.f / 8192.f, bid, tid, sS, sQ);
  else         stats2_body(P.wpart, P.wms, 512,  80,  1.f / 640.f,  bid - 8, tid, sS, sQ);
}

// ---------------------------------------------------------------------------
// cast: video BN apply+cast (0..8191) | words BN->bf16 + Gram fp32 (8192..8223)
// ---------------------------------------------------------------------------
__device__ __forceinline__ void cast_body(const MegaParams& P, int w, int tid) {
  if (w < 8192) {
    int i4 = w * 256 + tid;
    float4 v = reinterpret_cast<const float4*>(P.video)[i4];
    int c = (i4 & 255) * 4;
    v.x = (v.x - P.vms[c+0]) * P.vms[1024+c+0];
    v.y = (v.y - P.vms[c+1]) * P.vms[1024+c+1];
    v.z = (v.z - P.vms[c+2]) * P.vms[1024+c+2];
    v.w = (v.w - P.vms[c+3]) * P.vms[1024+c+3];
    ushort4_t h = { f2bf(v.x), f2bf(v.y), f2bf(v.z), f2bf(v.w) };
    reinterpret_cast<ushort4_t*>(P.vbf)[i4] = h;
  } else {
    int i = w - 8192;                        // sentence
    const float* wr = P.words + (size_t)i * L_ * DJ_;
    unsigned short* wb = P.wbnb + (size_t)i * L_ * DJ_;
    for (int idx = tid; idx < L_ * DJ_; idx += 256) {
      int d = idx & 511;
      wb[idx] = f2bf((wr[idx] - P.wms[d]) * P.wms[DJ_ + d]);
    }
    for (int p = tid; p < L_ * L_; p += 256) {
      int l = p / L_, l2 = p % L_;
      const float* a = wr + l * DJ_;
      const float* b = wr + l2 * DJ_;
      float acc = 0.f;
      for (int d = 0; d < DJ_; ++d) {
        float av = (a[d] - P.wms[d]) * P.wms[DJ_ + d];
        float bv = (b[d] - P.wms[d]) * P.wms[DJ_ + d];
        acc += av * bv;
      }
      P.G[i * 400 + p] = acc;
    }
  }
}

// ---------------------------------------------------------------------------
// MFMA bf16 GEMM stage (R9-verified body; linear shared via shraw).
// ---------------------------------------------------------------------------
template<int BM, int BN, bool RELU, bool BIAS, bool OUT_BF16, bool PARTIAL, bool STATS>
__device__ __forceinline__ void gemm_stage(
    char* shraw, int lin, int gx, int gy, int gz,
    const unsigned short* __restrict__ xin, const unsigned short* __restrict__ Wr,
    const float* __restrict__ bias, void* __restrict__ out, float* __restrict__ spart,
    int b_stride, int row_off, int row_t_stride,
    int To, int M, int t_off_out, int ldout, int Ktot, int Kloc)
{
  constexpr int AI = BM / 64, BI = BN / 64;     // staging issues per side
  constexpr int FM = BM / 32, FN = BN / 32;     // frags per wave
  short* As   = (short*)shraw;                        // 2*BM*32 shorts
  short* Bs   = (short*)(shraw + (size_t)2 * BM * 32 * 2);
  float* wred = (float*)(shraw + 24576);

  const int tid  = threadIdx.x;
  const int lane = tid & 63;
  const int wv   = tid >> 6;
  const int wr   = wv >> 1;
  const int wc   = wv & 1;

  // bijective XCD swizzle (m204)
  const int nwg = gx * gy * gz;
  const int q = nwg >> 3, r = nwg & 7;
  const int xcd = lin & 7, sub = lin >> 3;
  const int work = (xcd < r ? xcd * (q + 1) : r * (q + 1) + (xcd - r) * q) + sub;
  const int bx = work % gx;
  const int by = (work / gx) % gy;
  const int bz = work / (gx * gy);

  const int mbase = bx * BM;
  const int nbase = by * BN;
  const int kstart = PARTIAL ? bz * Kloc : 0;

  const int srow = tid >> 2;                       // 0..63
  const int sb   = (((tid & 3) ^ ((srow ^ (srow >> 2)) & 3))) * 8;
  const unsigned short* agp[AI];
  const unsigned short* bgp[BI];
#pragma unroll
  for (int i = 0; i < AI; ++i) {
    int ma = min(mbase + i * 64 + srow, M - 1);
    int b0 = ma / To, t0 = ma % To;
    agp[i] = xin + (size_t)b0 * b_stride + row_off
             + (size_t)t0 * row_t_stride + sb + kstart;
  }
#pragma unroll
  for (int i = 0; i < BI; ++i)
    bgp[i] = Wr + (size_t)(nbase + i * 64 + srow) * Ktot + sb + kstart;

  f32x4 acc[FM][FN] = {};
  const int nsteps = Kloc >> 5;

#define STAGE_(buf, k0)                                                        \
  do {                                                                         \
    _Pragma("unroll")                                                          \
    for (int i = 0; i < AI; ++i)                                               \
      GLOAD_LDS16(agp[i] + (k0), &As[(buf) * (BM * 32) + i * 2048 + wv * 512]);\
    _Pragma("unroll")                                                          \
    for (int i = 0; i < BI; ++i)                                               \
      GLOAD_LDS16(bgp[i] + (k0), &Bs[(buf) * (BN * 32) + i * 2048 + wv * 512]);\
  } while (0)

  STAGE_(0, 0);
  __syncthreads();

  const int l15   = lane & 15;
  const int rsw   = (l15 ^ (l15 >> 2)) & 3;
  const int chunk = ((lane >> 4) ^ rsw) * 8;
  const int a_off = (wr * (BM / 2) + l15) * 32 + chunk;
  const int b_off = (wc * (BN / 2) + l15) * 32 + chunk;

  for (int s = 0; s < nsteps; ++s) {
    const int nb = s & 1;
    if (s + 1 < nsteps) STAGE_(nb ^ 1, (s + 1) * 32);

    const short* Ab = &As[nb * (BM * 32) + a_off];
    const short* Bb = &Bs[nb * (BN * 32) + b_off];
    short8 af[FM], bf[FN];
#pragma unroll
    for (int f = 0; f < FM; ++f)
      af[f] = *reinterpret_cast<const short8*>(Ab + f * 512);
#pragma unroll
    for (int f = 0; f < FN; ++f)
      bf[f] = *reinterpret_cast<const short8*>(Bb + f * 512);
#pragma unroll
    for (int fm = 0; fm < FM; ++fm)
#pragma unroll
      for (int fn = 0; fn < FN; ++fn)
        acc[fm][fn] = __builtin_amdgcn_mfma_f32_16x16x32_bf16(af[fm], bf[fn], acc[fm][fn], 0, 0, 0);

    __syncthreads();
  }
#undef STAGE_

  // epilogue: C/D map col=lane&15, row=4*(lane>>4)+reg
  const int cl = lane & 15, rh = lane >> 4;
  float ls[FN], lq[FN];
#pragma unroll
  for (int f = 0; f < FN; ++f) { ls[f] = 0.f; lq[f] = 0.f; }
#pragma unroll
  for (int fm = 0; fm < FM; ++fm) {
#pragma unroll
    for (int fn = 0; fn < FN; ++fn) {
      int col = nbase + wc * (BN / 2) + fn * 16 + cl;
      float bv = BIAS ? bias[col] : 0.f;
      f32x4 v = acc[fm][fn];
#pragma unroll
      for (int rr = 0; rr < 4; ++rr) {
        int m = mbase + wr * (BM / 2) + fm * 16 + rh * 4 + rr;
        if (m < M) {
          if (PARTIAL) {
            float* pout = (float*)out + (size_t)bz * ((size_t)M * ldout);
            pout[(size_t)m * ldout + col] = v[rr];
          } else {
            int b = m / To, to = m % To;
            float x = v[rr] + bv;
            if (RELU) x = fmaxf(x, 0.f);
            size_t oi = ((size_t)b * TP_ + t_off_out + to) * (size_t)ldout + col;
            if (OUT_BF16) ((unsigned short*)out)[oi] = f2bf(x);
            else          ((float*)out)[oi] = x;
            if (STATS) { ls[fn] += x; lq[fn] += x * x; }
          }
        }
      }
    }
  }

  if (STATS) {   // deterministic per-block column stats (BM=BN=64 path)
#pragma unroll
    for (int fn = 0; fn < FN; ++fn) {
      float s = ls[fn], qq = lq[fn];
      s  += __shfl_xor(s, 16, 64);  qq += __shfl_xor(qq, 16, 64);
      s  += __shfl_xor(s, 32, 64);  qq += __shfl_xor(qq, 32, 64);
      if (rh == 0) {
        wred[wv * 64 + fn * 16 + cl]      = s;
        wred[wv * 64 + 32 + fn * 16 + cl] = qq;
      }
    }
    __syncthreads();
    if (tid < 64) {
      int wc2 = tid >> 5, cl2 = tid & 31;
      float s  = wred[wc2 * 64 + cl2]      + wred[(wc2 + 2) * 64 + cl2];
      float qq = wred[wc2 * 64 + 32 + cl2] + wred[(wc2 + 2) * 64 + 32 + cl2];
      int chan = nbase + wc2 * 32 + cl2;
      spart[(size_t)bx * 1024 + chan]       = s;
      spart[(size_t)bx * 1024 + 512 + chan] = qq;
    }
    __syncthreads();
  }
}

// ---------------------------------------------------------------------------
// K-split reduce body
// ---------------------------------------------------------------------------
template<int S>
__device__ __forceinline__ void red_body(const float* __restrict__ part,
                                         const float* __restrict__ bias,
                                         unsigned short* __restrict__ outb,
                                         int M, int To, int t_off_out,
                                         int w, int tid) {
  int idx = w * 256 + tid;
  int m = idx >> 7, n4 = idx & 127;
  if (m >= M) return;
  size_t off = (size_t)m * 512 + n4 * 4;
  float4 a = *reinterpret_cast<const float4*>(part + off);
#pragma unroll
  for (int s = 1; s < S; ++s) {
    float4 b = *reinterpret_cast<const float4*>(part + (size_t)s * M * 512 + off);
    a.x += b.x; a.y += b.y; a.z += b.z; a.w += b.w;
  }
  float4 bv = *reinterpret_cast<const float4*>(bias + n4 * 4);
  a.x = fmaxf(a.x + bv.x, 0.f);
  a.y = fmaxf(a.y + bv.y, 0.f);
  a.z = fmaxf(a.z + bv.z, 0.f);
  a.w = fmaxf(a.w + bv.w, 0.f);
  int b_ = m / To, to = m % To;
  ushort4_t h = { f2bf(a.x), f2bf(a.y), f2bf(a.z), f2bf(a.w) };
  reinterpret_cast<ushort4_t*>(outb + ((size_t)b_ * TP_ + t_off_out + to) * 512)[n4] = h;
}

// ---------------------------------------------------------------------------
// v2 normalize + bf16 + row norm: 4 rows per 256-thread block (one per wave)
// ---------------------------------------------------------------------------
__device__ __forceinline__ void v2norm_body(const MegaParams& P, int w, int tid) {
  int r = w * 4 + (tid >> 6);
  int t = tid & 63;
  float* row = P.v2 + (size_t)r * DJ_;
  unsigned short* brow = P.v2bf + (size_t)r * DJ_;
  const float* ms = P.v2ms;
  float ss = 0.f;
#pragma unroll
  for (int h = 0; h < 2; ++h) {
    int c4 = t + h * 64;
    float4 v = reinterpret_cast<float4*>(row)[c4];
    int c = c4 * 4;
    v.x = (v.x - ms[c+0]) * ms[DJ_+c+0];
    v.y = (v.y - ms[c+1]) * ms[DJ_+c+1];
    v.z = (v.z - ms[c+2]) * ms[DJ_+c+2];
    v.w = (v.w - ms[c+3]) * ms[DJ_+c+3];
    reinterpret_cast<float4*>(row)[c4] = v;
    ushort4_t h4 = { f2bf(v.x), f2bf(v.y), f2bf(v.z), f2bf(v.w) };
    reinterpret_cast<ushort4_t*>(brow)[c4] = h4;
    ss += v.x*v.x + v.y*v.y + v.z*v.z + v.w*v.w;
  }
#pragma unroll
  for (int o = 32; o; o >>= 1) ss += __shfl_down(ss, o, 64);
  if (t == 0) P.vn[r] = sqrtf(ss);
}

// ---------------------------------------------------------------------------
// sim body (w = j + 32*i)
// ---------------------------------------------------------------------------
__device__ __forceinline__ void sim_body(const MegaParams& P, int w, int tid,
                                         char* shraw) {
  float* sG  = (float*)shraw;        // 400
  float* sm  = sG + 400;             // 20
  float* red = sm + 20;              // 4
  int j = w & 31, i = w >> 5;
  for (int p = tid; p < 400; p += 256) sG[p] = P.G[i * 400 + p];
  if (tid < 20) sm[tid] = P.wmask[i * 20 + tid];
  __syncthreads();

  float simv = -1e30f;
  if (tid < TP_) {
    const float* ar = P.Amat + ((size_t)j * TP_ + tid) * 640 + i * 20;
    float a[20], p[20];
    float mx = -1e30f;
#pragma unroll
    for (int l = 0; l < 20; ++l) {
      a[l] = ar[l];
      float lg = (sm[l] > 0.5f) ? LAM_ * a[l] : -1e9f;
      p[l] = lg;
      mx = fmaxf(mx, lg);
    }
    float Z = 0.f;
#pragma unroll
    for (int l = 0; l < 20; ++l) { p[l] = __expf(p[l] - mx); Z += p[l]; }
    float invZ = 1.f / Z, num = 0.f;
#pragma unroll
    for (int l = 0; l < 20; ++l) { p[l] *= invZ; num += p[l] * a[l]; }
    float q2 = 0.f;
#pragma unroll
    for (int l = 0; l < 20; ++l) {
      float gi = 0.f;
#pragma unroll
      for (int l2 = 0; l2 < 20; ++l2) gi += sG[l * 20 + l2] * p[l2];
      q2 += p[l] * gi;
    }
    float vnv = fmaxf(P.vn[(size_t)j * TP_ + tid], 1e-8f);
    float vsnv = fmaxf(sqrtf(q2), 1e-8f);
    simv = num / (vnv * vsnv);
    if (i == j) P.out[1 + i * TP_ + tid] = simv;
  }
  float mv = simv;
#pragma unroll
  for (int o = 32; o; o >>= 1) mv = fmaxf(mv, __shfl_down(mv, o, 64));
  if ((tid & 63) == 0) red[tid >> 6] = mv;
  __syncthreads();
  if (tid == 0)
    P.scores[i * 32 + j] = fmaxf(fmaxf(red[0], red[1]), fmaxf(red[2], red[3]));
  __syncthreads();
}

// loss over scores[32][32] with 256 threads
__device__ __forceinline__ void loss_body(const MegaParams& P, int tid, char* shraw) {
  float* red = (float*)shraw;
  const float* s = P.scores;
  float c = 0.f;
  for (int p = tid; p < 1024; p += 256) {
    int i = p >> 5, j = p & 31;
    float sv = s[p];
    if (i != j)
      c += fmaxf(0.f, MARGIN_ + sv - s[i * 32 + i]) +
           fmaxf(0.f, MARGIN_ + sv - s[j * 32 + j]);
  }
#pragma unroll
  for (int o = 32; o; o >>= 1) c += __shfl_down(c, o, 64);
  if ((tid & 63) == 0) red[tid >> 6] = c;
  __syncthreads();
  if (tid == 0) P.out[0] = (red[0] + red[1] + red[2] + red[3]) / 32.f;
}

// ---------------------------------------------------------------------------
// MEGA kernel: all 15 stages, grid-wide sync between.  1024 blocks, 4/CU.
// ---------------------------------------------------------------------------
__global__ __launch_bounds__(256, 4) void mega_k(MegaParams P) {
  __shared__ __align__(16) char shraw[SHBYTES];
  cg::grid_group gg = cg::this_grid();
  const int tid = threadIdx.x;
  const int bid = blockIdx.x;
#define GS() do { __threadfence(); gg.sync(); } while (0)

  // 1: weight reorder + video/words stats1
  for (int w = bid; w < 4904; w += NB_) prep_body(P, w, tid);
  GS();
  // 2: video + words stats2
  if (bid < 12) stats2c_body(P, bid, tid, shraw);
  GS();
  // 3: video BN cast + words BN->bf16 + Gram
  for (int w = bid; w < 8224; w += NB_) cast_body(P, w, tid);
  GS();
  // 4: conv0 partial  (64,4,4)=1024, 64x128, K 4x1024
  for (int w = bid; w < 1024; w += NB_)
    gemm_stage<64,128,false,false,false,true,false>(shraw, w, 64, 4, 4,
      P.vbf, P.W0, nullptr, P.Pbuf, nullptr, 262144, 0, 2048,
      T0_, 32 * T0_, 0, 512, 4096, 1024);
  GS();
  // 5: reduce conv0
  for (int w = bid; w < 2032; w += NB_)
    red_body<4>(P.Pbuf, P.c0b, P.vcb, 32 * T0_, T0_, 0, w, tid);
  GS();
  // 6: conv1 partial  (31,4,8)=992, 64x128, K 8x256
  for (int w = bid; w < 992; w += NB_)
    gemm_stage<64,128,false,false,false,true,false>(shraw, w, 31, 4, 8,
      P.vcb, P.W1, nullptr, P.Pbuf, nullptr, 112128, 0, 1024,
      T1_, 32 * T1_, 0, 512, 2048, 256);
  GS();
  // 7: reduce conv1
  for (int w = bid; w < 992; w += NB_)
    red_body<8>(P.Pbuf, P.c1b, P.vcb, 32 * T1_, T1_, T0_, w, tid);
  GS();
  // 8: conv2 partial  (15,8,8)=960, 64x64, K 8x256
  for (int w = bid; w < 960; w += NB_)
    gemm_stage<64,64,false,false,false,true,false>(shraw, w, 15, 8, 8,
      P.vcb, P.W2, nullptr, P.Pbuf, nullptr, 112128, 65024, 1024,
      T2_, 32 * T2_, 0, 512, 2048, 256);
  GS();
  // 9: reduce conv2
  for (int w = bid; w < 480; w += NB_)
    red_body<8>(P.Pbuf, P.c2b, P.vcb, 32 * T2_, T2_, T0_ + T1_, w, tid);
  GS();
  // 10: pointwise conv -> v2 fp32 + fused stats1 epilogue  (110,8)=880
  for (int w = bid; w < 880; w += NB_)
    gemm_stage<64,64,false,true,false,false,true>(shraw, w, 110, 8, 1,
      P.vcb, P.Wp, P.pwb, P.v2, P.v2part, 112128, 0, 512,
      TP_, 32 * TP_, 0, 512, 512, 512);
  GS();
  // 11: v2 stats2
  if (bid < 4)
    stats2_body(P.v2part, P.v2ms, 512, 110, 1.f / 7008.f, bid, tid,
                (float4*)shraw, (float4*)shraw + 264);
  GS();
  // 12: v2 BN apply + bf16 + row norms (1752 x 4 rows)
  for (int w = bid; w < 1752; w += NB_) v2norm_body(P, w, tid);
  GS();
  // 13: attention A = v.w  (110,10)=1100, 64x64
  for (int w = bid; w < 1100; w += NB_)
    gemm_stage<64,64,false,false,false,false,false>(shraw, w, 110, 10, 1,
      P.v2bf, P.wbnb, nullptr, P.Amat, nullptr, 112128, 0, 512,
      TP_, 32 * TP_, 0, 640, 512, 512);
  GS();
  // 14: sim / scores / positive map
  for (int w = bid; w < 1024; w += NB_) sim_body(P, w, tid, shraw);
  GS();
  // 15: loss
  if (bid == 0) loss_body(P, tid, shraw);
#undef GS
}

// ---------------------------------------------------------------------------
// Fallback wrappers (R9 launch sequence) in case cooperative launch fails.
// ---------------------------------------------------------------------------
__global__ __launch_bounds__(256) void prep_g(MegaParams P) {
  prep_body(P, blockIdx.x, threadIdx.x);
}
__global__ __launch_bounds__(256) void stats2c_g(MegaParams P) {
  __shared__ __align__(16) char shraw[8448];
  stats2c_body(P, blockIdx.x, threadIdx.x, shraw);
}
__global__ __launch_bounds__(256) void cast_g(MegaParams P) {
  cast_body(P, blockIdx.x, threadIdx.x);
}
template<int BM, int BN, bool RELU, bool BIAS, bool OUT_BF16, bool PARTIAL, bool STATS>
__global__ __launch_bounds__(256) void gemm_g(
    const unsigned short* xin, const unsigned short* Wr, const float* bias,
    void* out, float* spart, int b_stride, int row_off, int row_t_stride,
    int To, int M, int t_off_out, int ldout, int Ktot, int Kloc) {
  __shared__ __align__(16) char shraw[SHBYTES];
  int lin = blockIdx.x + gridDim.x * (blockIdx.y + gridDim.y * blockIdx.z);
  gemm_stage<BM,BN,RELU,BIAS,OUT_BF16,PARTIAL,STATS>(
      shraw, lin, gridDim.x, gridDim.y, gridDim.z, xin, Wr, bias, out, spart,
      b_stride, row_off, row_t_stride, To, M, t_off_out, ldout, Ktot, Kloc);
}
template<int S>
__global__ __launch_bounds__(256) void red_g(const float* part, const float* bias,
                                             unsigned short* outb,
                                             int M, int To, int t_off_out) {
  red_body<S>(part, bias, outb, M, To, t_off_out, blockIdx.x, threadIdx.x);
}
__global__ __launch_bounds__(256) void stats2v_g(MegaParams P) {
  __shared__ __align__(16) char shraw[8448];
  stats2_body(P.v2part, P.v2ms, 512, 110, 1.f / 7008.f, blockIdx.x, threadIdx.x,
              (float4*)shraw, (float4*)shraw + 264);
}
__global__ __launch_bounds__(256) void v2norm_g(MegaParams P) {
  v2norm_body(P, blockIdx.x, threadIdx.x);
}
__global__ __launch_bounds__(256) void sim_g(MegaParams P) {
  __shared__ __align__(16) char shraw[1696];
  sim_body(P, blockIdx.x, threadIdx.x, shraw);
}
__global__ __launch_bounds__(256) void loss_g(MegaParams P) {
  __shared__ __align__(16) char shraw[64];
  loss_body(P, threadIdx.x, shraw);
}

// ---------------------------------------------------------------------------
extern "C" void kernel_launch(void* const* d_in, const int* in_sizes, int n_in,
                              void* d_out, int out_size, void* d_ws, size_t ws_size,
                              hipStream_t stream) {
  float* ws = (float*)d_ws;

  // ---- workspace layout (float units); identical to R9 (fixed wbnb size) --
  float*          W0r    = ws;                       // 1048576
  float*          W1r    = W0r + 1048576;            // 524288
  float*          W2r    = W1r + 524288;             // 524288
  float*          Wpw    = W2r + 524288;             // 131072
  float*          AMvbf  = Wpw + 131072;             // 4485120 (vbf | Amat)
  float*          vcatb  = AMvbf + 4485120;          // 1794048 (bf16 vcat)
  float*          Pbuf   = vcatb + 1794048;          // 8323072 overlay:
  float*          v2     = Pbuf;                     //   3588096
  float*          v2bfp  = v2 + 3588096;             //   1794048
  float*          v2part = v2bfp + 1794048;          //   112640
  float*          v2ms   = v2part + 112640;          //   1024
  float*          vpart  = v2ms + 1024;              //   1048576
  float*          vms    = vpart + 1048576;          //   2048
  float*          wpart  = vms + 2048;               //   81920
  float*          wms    = wpart + 81920;            //   1024 (fits 8323072)
  float*          endPb  = Pbuf + 8323072;
  float*          wbnbp  = endPb;                    // 163840 (bf16 327680)
  float*          G      = wbnbp + 163840;           // 12800
  float*          vn     = G + 12800;                // 7008
  float*          scores = vn + 7008;                // 1024

  MegaParams P;
  P.video = (const float*)d_in[0];
  P.words = (const float*)d_in[1];
  P.wmask = (const float*)d_in[2];
  P.c0w = (const float*)d_in[3];  P.c0b = (const float*)d_in[4];
  P.c1w = (const float*)d_in[5];  P.c1b = (const float*)d_in[6];
  P.c2w = (const float*)d_in[7];  P.c2b = (const float*)d_in[8];
  P.pww = (const float*)d_in[9];  P.pwb = (const float*)d_in[10];
  P.out = (float*)d_out;
  P.W0 = (unsigned short*)W0r;  P.W1 = (unsigned short*)W1r;
  P.W2 = (unsigned short*)W2r;  P.Wp = (unsigned short*)Wpw;
  P.vbf = (unsigned short*)AMvbf;
  P.vcb = (unsigned short*)vcatb;
  P.v2bf = (unsigned short*)v2bfp;
  P.wbnb = (unsigned short*)wbnbp;
  P.Amat = AMvbf;   P.Pbuf = Pbuf;   P.v2 = v2;
  P.v2part = v2part; P.v2ms = v2ms;  P.vpart = vpart; P.vms = vms;
  P.wpart = wpart;  P.wms = wms;     P.G = G; P.vn = vn; P.scores = scores;

  void* args[] = { &P };
  hipError_t err = hipLaunchCooperativeKernel((const void*)mega_k,
                                              dim3(NB_), dim3(256), args, 0, stream);
  if (err == hipSuccess) return;

  // ---- fallback: R9-equivalent 15-launch sequence ----
  prep_g<<<4904, 256, 0, stream>>>(P);
  stats2c_g<<<12, 256, 0, stream>>>(P);
  cast_g<<<8224, 256, 0, stream>>>(P);
  gemm_g<64,128,false,false,false,true,false><<<dim3(64, 4, 4), 256, 0, stream>>>(
      P.vbf, P.W0, nullptr, P.Pbuf, nullptr, 262144, 0, 2048, T0_, 32 * T0_, 0, 512, 4096, 1024);
  red_g<4><<<2032, 256, 0, stream>>>(P.Pbuf, P.c0b, P.vcb, 32 * T0_, T0_, 0);
  gemm_g<64,128,false,false,false,true,false><<<dim3(31, 4, 8), 256, 0, stream>>>(
      P.vcb, P.W1, nullptr, P.Pbuf, nullptr, 112128, 0, 1024, T1_, 32 * T1_, 0, 512, 2048, 256);
  red_g<8><<<992, 256, 0, stream>>>(P.Pbuf, P.c1b, P.vcb, 32 * T1_, T1_, T0_);
  gemm_g<64,64,false,false,false,true,false><<<dim3(15, 8, 8), 256, 0, stream>>>(
      P.vcb, P.W2, nullptr, P.Pbuf, nullptr, 112128, 65024, 1024, T2_, 32 * T2_, 0, 512, 2048, 256);
  red_g<8><<<480, 256, 0, stream>>>(P.Pbuf, P.c2b, P.vcb, 32 * T2_, T2_, T0_ + T1_);
  gemm_g<64,64,false,true,false,false,true><<<dim3(110, 8), 256, 0, stream>>>(
      P.vcb, P.Wp, P.pwb, P.v2, P.v2part, 112128, 0, 512, TP_, 32 * TP_, 0, 512, 512, 512);
  stats2v_g<<<4, 256, 0, stream>>>(P);
  v2norm_g<<<1752, 256, 0, stream>>>(P);
  gemm_g<64,64,false,false,false,false,false><<<dim3(110, 10), 256, 0, stream>>>(
      P.v2bf, P.wbnb, nullptr, P.Amat, nullptr, 112128, 0, 512, TP_, 32 * TP_, 0, 640, 512, 512);
  sim_g<<<1024, 256, 0, stream>>>(P);
  loss_g<<<1, 256, 0, stream>>>(P);
}

// Round 11
// 388.274 us; speedup vs baseline: 7.7702x; 7.7702x over previous
//
#include <hip/hip_runtime.h>
#include <math.h>

// Problem constants
#define B_   32
#define T_   256
#define DV_  1024
#define DJ_  512
#define L_   20
#define T0_  127
#define T1_  62
#define T2_  30
#define TP_  219          // 127+62+30
#define LAM_ 4.0f
#define MARGIN_ 0.1f
#define SHBYTES 25600     // 24KB gemm dbuf + 1KB wred

typedef __attribute__((ext_vector_type(8))) short short8;
typedef __attribute__((ext_vector_type(4))) float f32x4;

static __device__ __forceinline__ unsigned short f2bf(float f) {
  union { float f; unsigned u; } v; v.f = f;
  unsigned r = v.u + 0x7fff + ((v.u >> 16) & 1);   // round-to-nearest-even
  return (unsigned short)(r >> 16);
}

struct ushort4_t { unsigned short x, y, z, w; };

#define GLOAD_LDS16(gp, lp)                                                      \
  __builtin_amdgcn_global_load_lds(                                              \
      (const __attribute__((address_space(1))) void*)(gp),                       \
      (__attribute__((address_space(3))) void*)(lp), 16, 0, 0)

// ---------------------------------------------------------------------------
struct MegaParams {
  const float *video, *words, *wmask;
  const float *c0w, *c0b, *c1w, *c1b, *c2w, *c2b, *pww, *pwb;
  float* out;
  unsigned short *W0, *W1, *W2, *Wp, *vbf, *vcb, *v2bf, *wbnb;
  float *Amat, *Pbuf, *v2, *v2part, *v2ms, *vpart, *vms, *wpart, *wms,
        *G, *vn, *scores;
  unsigned *cnt_pw, *cnt_sim;
};

// ---------------------------------------------------------------------------
// BatchNorm stats bodies (deterministic two-stage).  [HW-verified R10]
// ---------------------------------------------------------------------------
__device__ __forceinline__ void stats1_body(const float* __restrict__ x,
                                            float* __restrict__ part,
                                            int C, int rows, int rpg, int cpgShift,
                                            int bid, int tid) {
  int cpg  = 1 << cpgShift;                 // C/4
  int c4   = tid & (cpg - 1);
  int rsub = tid >> cpgShift;
  int nsub = 256 >> cpgShift;
  int r0 = bid * rpg + rsub;
  int r1 = min(bid * rpg + rpg, rows);
  float4 s = {0.f,0.f,0.f,0.f}, q = {0.f,0.f,0.f,0.f};
  for (int r = r0; r < r1; r += nsub) {
    float4 v = *reinterpret_cast<const float4*>(&x[(size_t)r * C + c4 * 4]);
    s.x += v.x; s.y += v.y; s.z += v.z; s.w += v.w;
    q.x += v.x*v.x; q.y += v.y*v.y; q.z += v.z*v.z; q.w += v.w*v.w;
  }
  float* ps = part + ((size_t)bid * nsub + rsub) * 2 * C;
  reinterpret_cast<float4*>(ps)[c4] = s;
  reinterpret_cast<float4*>(ps + C)[c4] = q;
}

__device__ __forceinline__ void stats2_body(const float* __restrict__ part,
                                            float* __restrict__ ms,
                                            int C, int ng, float inv_n,
                                            int bid, int tid,
                                            float4* sS, float4* sQ) {
  int c4l = tid & 31;
  int gs  = tid >> 5;
  int c4  = bid * 32 + c4l;                 // float4 channel index
  float4 s = {0.f,0.f,0.f,0.f}, q = {0.f,0.f,0.f,0.f};
  for (int g = gs; g < ng; g += 8) {
    const float4* ps = reinterpret_cast<const float4*>(part + (size_t)g * 2 * C);
    float4 a = ps[c4];
    float4 b = ps[(C >> 2) + c4];
    s.x += a.x; s.y += a.y; s.z += a.z; s.w += a.w;
    q.x += b.x; q.y += b.y; q.z += b.z; q.w += b.w;
  }
  sS[gs * 33 + c4l] = s; sQ[gs * 33 + c4l] = q;
  __syncthreads();
  if (gs == 0) {
    float4 S = sS[c4l], Q = sQ[c4l];
#pragma unroll
    for (int k = 1; k < 8; ++k) {
      float4 a = sS[k * 33 + c4l], b = sQ[k * 33 + c4l];
      S.x += a.x; S.y += a.y; S.z += a.z; S.w += a.w;
      Q.x += b.x; Q.y += b.y; Q.z += b.z; Q.w += b.w;
    }
    int c = c4 * 4;
    float m0 = S.x * inv_n, m1 = S.y * inv_n, m2 = S.z * inv_n, m3 = S.w * inv_n;
    ms[c+0] = m0; ms[C+c+0] = rsqrtf(Q.x * inv_n - m0*m0 + 1e-5f);
    ms[c+1] = m1; ms[C+c+1] = rsqrtf(Q.y * inv_n - m1*m1 + 1e-5f);
    ms[c+2] = m2; ms[C+c+2] = rsqrtf(Q.z * inv_n - m2*m2 + 1e-5f);
    ms[c+3] = m3; ms[C+c+3] = rsqrtf(Q.w * inv_n - m3*m3 + 1e-5f);
  }
}

// ---------------------------------------------------------------------------
// prep: weight reorder+cast | video stats1 | words stats1 | counter zeroing.
// ---------------------------------------------------------------------------
__device__ __forceinline__ void prep_body(const MegaParams& P, int bid, int tid) {
  if (bid == 0 && tid == 0) { P.cnt_pw[0] = 0u; P.cnt_sim[0] = 0u; }
  if (bid < 2048) {            // conv0: 512*1024 (co,ci) pairs
    int idx = bid * 256 + tid;
    int co = idx >> 10, ci = idx & 1023;
    float4 w = *reinterpret_cast<const float4*>(P.c0w + (size_t)idx * 4);
    unsigned short* d = P.W0 + (size_t)co * 4096 + ci;
    d[0] = f2bf(w.x); d[1024] = f2bf(w.y); d[2048] = f2bf(w.z); d[3072] = f2bf(w.w);
  } else if (bid < 3072) {     // conv1
    int idx = (bid - 2048) * 256 + tid;
    int co = idx >> 9, ci = idx & 511;
    float4 w = *reinterpret_cast<const float4*>(P.c1w + (size_t)idx * 4);
    unsigned short* d = P.W1 + (size_t)co * 2048 + ci;
    d[0] = f2bf(w.x); d[512] = f2bf(w.y); d[1024] = f2bf(w.z); d[1536] = f2bf(w.w);
  } else if (bid < 4096) {     // conv2
    int idx = (bid - 3072) * 256 + tid;
    int co = idx >> 9, ci = idx & 511;
    float4 w = *reinterpret_cast<const float4*>(P.c2w + (size_t)idx * 4);
    unsigned short* d = P.W2 + (size_t)co * 2048 + ci;
    d[0] = f2bf(w.x); d[512] = f2bf(w.y); d[1024] = f2bf(w.z); d[1536] = f2bf(w.w);
  } else if (bid < 4352) {     // pw identity cast
    int idx = (bid - 4096) * 256 + tid;
    float4 v = *reinterpret_cast<const float4*>(P.pww + (size_t)idx * 4);
    ushort4_t h = { f2bf(v.x), f2bf(v.y), f2bf(v.z), f2bf(v.w) };
    reinterpret_cast<ushort4_t*>(P.Wp)[idx] = h;
  } else if (bid < 4864) {     // video stats1
    stats1_body(P.video, P.vpart, 1024, 8192, 16, 8, bid - 4352, tid);
  } else {                     // words stats1
    stats1_body(P.words, P.wpart, 512, 640, 16, 7, bid - 4864, tid);
  }
}

__device__ __forceinline__ void stats2c_body(const MegaParams& P, int bid, int tid,
                                             char* shraw) {
  float4* sS = (float4*)shraw;
  float4* sQ = sS + 264;
  if (bid < 8) stats2_body(P.vpart, P.vms, 1024, 512, 1.f / 8192.f, bid, tid, sS, sQ);
  else         stats2_body(P.wpart, P.wms, 512,  80,  1.f / 640.f,  bid - 8, tid, sS, sQ);
}

// ---------------------------------------------------------------------------
// cast: video BN apply+cast (0..8191) | words BN->bf16 + Gram fp32 (8192..8223)
// ---------------------------------------------------------------------------
__device__ __forceinline__ void cast_body(const MegaParams& P, int w, int tid) {
  if (w < 8192) {
    int i4 = w * 256 + tid;
    float4 v = reinterpret_cast<const float4*>(P.video)[i4];
    int c = (i4 & 255) * 4;
    v.x = (v.x - P.vms[c+0]) * P.vms[1024+c+0];
    v.y = (v.y - P.vms[c+1]) * P.vms[1024+c+1];
    v.z = (v.z - P.vms[c+2]) * P.vms[1024+c+2];
    v.w = (v.w - P.vms[c+3]) * P.vms[1024+c+3];
    ushort4_t h = { f2bf(v.x), f2bf(v.y), f2bf(v.z), f2bf(v.w) };
    reinterpret_cast<ushort4_t*>(P.vbf)[i4] = h;
  } else {
    int i = w - 8192;                        // sentence
    const float* wr = P.words + (size_t)i * L_ * DJ_;
    unsigned short* wb = P.wbnb + (size_t)i * L_ * DJ_;
    for (int idx = tid; idx < L_ * DJ_; idx += 256) {
      int d = idx & 511;
      wb[idx] = f2bf((wr[idx] - P.wms[d]) * P.wms[DJ_ + d]);
    }
    for (int p = tid; p < L_ * L_; p += 256) {
      int l = p / L_, l2 = p % L_;
      const float* a = wr + l * DJ_;
      const float* b = wr + l2 * DJ_;
      float acc = 0.f;
      for (int d = 0; d < DJ_; ++d) {
        float av = (a[d] - P.wms[d]) * P.wms[DJ_ + d];
        float bv = (b[d] - P.wms[d]) * P.wms[DJ_ + d];
        acc += av * bv;
      }
      P.G[i * 400 + p] = acc;
    }
  }
}

// ---------------------------------------------------------------------------
// MFMA bf16 GEMM stage.  [HW-verified R9/R10]
// ---------------------------------------------------------------------------
template<int BM, int BN, bool RELU, bool BIAS, bool OUT_BF16, bool PARTIAL, bool STATS>
__device__ __forceinline__ void gemm_stage(
    char* shraw, int lin, int gx, int gy, int gz,
    const unsigned short* __restrict__ xin, const unsigned short* __restrict__ Wr,
    const float* __restrict__ bias, void* __restrict__ out, float* __restrict__ spart,
    int b_stride, int row_off, int row_t_stride,
    int To, int M, int t_off_out, int ldout, int Ktot, int Kloc)
{
  constexpr int AI = BM / 64, BI = BN / 64;     // staging issues per side
  constexpr int FM = BM / 32, FN = BN / 32;     // frags per wave
  short* As   = (short*)shraw;                        // 2*BM*32 shorts
  short* Bs   = (short*)(shraw + (size_t)2 * BM * 32 * 2);
  float* wred = (float*)(shraw + 24576);

  const int tid  = threadIdx.x;
  const int lane = tid & 63;
  const int wv   = tid >> 6;
  const int wr   = wv >> 1;
  const int wc   = wv & 1;

  // bijective XCD swizzle (m204)
  const int nwg = gx * gy * gz;
  const int q = nwg >> 3, r = nwg & 7;
  const int xcd = lin & 7, sub = lin >> 3;
  const int work = (xcd < r ? xcd * (q + 1) : r * (q + 1) + (xcd - r) * q) + sub;
  const int bx = work % gx;
  const int by = (work / gx) % gy;
  const int bz = work / (gx * gy);

  const int mbase = bx * BM;
  const int nbase = by * BN;
  const int kstart = PARTIAL ? bz * Kloc : 0;

  const int srow = tid >> 2;                       // 0..63
  const int sb   = (((tid & 3) ^ ((srow ^ (srow >> 2)) & 3))) * 8;
  const unsigned short* agp[AI];
  const unsigned short* bgp[BI];
#pragma unroll
  for (int i = 0; i < AI; ++i) {
    int ma = min(mbase + i * 64 + srow, M - 1);
    int b0 = ma / To, t0 = ma % To;
    agp[i] = xin + (size_t)b0 * b_stride + row_off
             + (size_t)t0 * row_t_stride + sb + kstart;
  }
#pragma unroll
  for (int i = 0; i < BI; ++i)
    bgp[i] = Wr + (size_t)(nbase + i * 64 + srow) * Ktot + sb + kstart;

  f32x4 acc[FM][FN] = {};
  const int nsteps = Kloc >> 5;

#define STAGE_(buf, k0)                                                        \
  do {                                                                         \
    _Pragma("unroll")                                                          \
    for (int i = 0; i < AI; ++i)                                               \
      GLOAD_LDS16(agp[i] + (k0), &As[(buf) * (BM * 32) + i * 2048 + wv * 512]);\
    _Pragma("unroll")                                                          \
    for (int i = 0; i < BI; ++i)                                               \
      GLOAD_LDS16(bgp[i] + (k0), &Bs[(buf) * (BN * 32) + i * 2048 + wv * 512]);\
  } while (0)

  STAGE_(0, 0);
  __syncthreads();

  const int l15   = lane & 15;
  const int rsw   = (l15 ^ (l15 >> 2)) & 3;
  const int chunk = ((lane >> 4) ^ rsw) * 8;
  const int a_off = (wr * (BM / 2) + l15) * 32 + chunk;
  const int b_off = (wc * (BN / 2) + l15) * 32 + chunk;

  for (int s = 0; s < nsteps; ++s) {
    const int nb = s & 1;
    if (s + 1 < nsteps) STAGE_(nb ^ 1, (s + 1) * 32);

    const short* Ab = &As[nb * (BM * 32) + a_off];
    const short* Bb = &Bs[nb * (BN * 32) + b_off];
    short8 af[FM], bf[FN];
#pragma unroll
    for (int f = 0; f < FM; ++f)
      af[f] = *reinterpret_cast<const short8*>(Ab + f * 512);
#pragma unroll
    for (int f = 0; f < FN; ++f)
      bf[f] = *reinterpret_cast<const short8*>(Bb + f * 512);
#pragma unroll
    for (int fm = 0; fm < FM; ++fm)
#pragma unroll
      for (int fn = 0; fn < FN; ++fn)
        acc[fm][fn] = __builtin_amdgcn_mfma_f32_16x16x32_bf16(af[fm], bf[fn], acc[fm][fn], 0, 0, 0);

    __syncthreads();
  }
#undef STAGE_

  // epilogue: C/D map col=lane&15, row=4*(lane>>4)+reg
  const int cl = lane & 15, rh = lane >> 4;
  float ls[FN], lq[FN];
#pragma unroll
  for (int f = 0; f < FN; ++f) { ls[f] = 0.f; lq[f] = 0.f; }
#pragma unroll
  for (int fm = 0; fm < FM; ++fm) {
#pragma unroll
    for (int fn = 0; fn < FN; ++fn) {
      int col = nbase + wc * (BN / 2) + fn * 16 + cl;
      float bv = BIAS ? bias[col] : 0.f;
      f32x4 v = acc[fm][fn];
#pragma unroll
      for (int rr = 0; rr < 4; ++rr) {
        int m = mbase + wr * (BM / 2) + fm * 16 + rh * 4 + rr;
        if (m < M) {
          if (PARTIAL) {
            float* pout = (float*)out + (size_t)bz * ((size_t)M * ldout);
            pout[(size_t)m * ldout + col] = v[rr];
          } else {
            int b = m / To, to = m % To;
            float x = v[rr] + bv;
            if (RELU) x = fmaxf(x, 0.f);
            size_t oi = ((size_t)b * TP_ + t_off_out + to) * (size_t)ldout + col;
            if (OUT_BF16) ((unsigned short*)out)[oi] = f2bf(x);
            else          ((float*)out)[oi] = x;
            if (STATS) { ls[fn] += x; lq[fn] += x * x; }
          }
        }
      }
    }
  }

  if (STATS) {   // deterministic per-block column stats (BM=BN=64 path)
#pragma unroll
    for (int fn = 0; fn < FN; ++fn) {
      float s = ls[fn], qq = lq[fn];
      s  += __shfl_xor(s, 16, 64);  qq += __shfl_xor(qq, 16, 64);
      s  += __shfl_xor(s, 32, 64);  qq += __shfl_xor(qq, 32, 64);
      if (rh == 0) {
        wred[wv * 64 + fn * 16 + cl]      = s;
        wred[wv * 64 + 32 + fn * 16 + cl] = qq;
      }
    }
    __syncthreads();
    if (tid < 64) {
      int wc2 = tid >> 5, cl2 = tid & 31;
      float s  = wred[wc2 * 64 + cl2]      + wred[(wc2 + 2) * 64 + cl2];
      float qq = wred[wc2 * 64 + 32 + cl2] + wred[(wc2 + 2) * 64 + 32 + cl2];
      int chan = nbase + wc2 * 32 + cl2;
      spart[(size_t)bx * 1024 + chan]       = s;
      spart[(size_t)bx * 1024 + 512 + chan] = qq;
    }
    __syncthreads();
  }
}

// ---------------------------------------------------------------------------
// K-split reduce body
// ---------------------------------------------------------------------------
template<int S>
__device__ __forceinline__ void red_body(const float* __restrict__ part,
                                         const float* __restrict__ bias,
                                         unsigned short* __restrict__ outb,
                                         int M, int To, int t_off_out,
                                         int w, int tid) {
  int idx = w * 256 + tid;
  int m = idx >> 7, n4 = idx & 127;
  if (m >= M) return;
  size_t off = (size_t)m * 512 + n4 * 4;
  float4 a = *reinterpret_cast<const float4*>(part + off);
#pragma unroll
  for (int s = 1; s < S; ++s) {
    float4 b = *reinterpret_cast<const float4*>(part + (size_t)s * M * 512 + off);
    a.x += b.x; a.y += b.y; a.z += b.z; a.w += b.w;
  }
  float4 bv = *reinterpret_cast<const float4*>(bias + n4 * 4);
  a.x = fmaxf(a.x + bv.x, 0.f);
  a.y = fmaxf(a.y + bv.y, 0.f);
  a.z = fmaxf(a.z + bv.z, 0.f);
  a.w = fmaxf(a.w + bv.w, 0.f);
  int b_ = m / To, to = m % To;
  ushort4_t h = { f2bf(a.x), f2bf(a.y), f2bf(a.z), f2bf(a.w) };
  reinterpret_cast<ushort4_t*>(outb + ((size_t)b_ * TP_ + t_off_out + to) * 512)[n4] = h;
}

// ---------------------------------------------------------------------------
// v2 normalize + bf16 + row norm: 4 rows per 256-thread block
// ---------------------------------------------------------------------------
__device__ __forceinline__ void v2norm_body(const MegaParams& P, int w, int tid) {
  int r = w * 4 + (tid >> 6);
  int t = tid & 63;
  float* row = P.v2 + (size_t)r * DJ_;
  unsigned short* brow = P.v2bf + (size_t)r * DJ_;
  const float* ms = P.v2ms;
  float ss = 0.f;
#pragma unroll
  for (int h = 0; h < 2; ++h) {
    int c4 = t + h * 64;
    float4 v = reinterpret_cast<float4*>(row)[c4];
    int c = c4 * 4;
    v.x = (v.x - ms[c+0]) * ms[DJ_+c+0];
    v.y = (v.y - ms[c+1]) * ms[DJ_+c+1];
    v.z = (v.z - ms[c+2]) * ms[DJ_+c+2];
    v.w = (v.w - ms[c+3]) * ms[DJ_+c+3];
    reinterpret_cast<float4*>(row)[c4] = v;
    ushort4_t h4 = { f2bf(v.x), f2bf(v.y), f2bf(v.z), f2bf(v.w) };
    reinterpret_cast<ushort4_t*>(brow)[c4] = h4;
    ss += v.x*v.x + v.y*v.y + v.z*v.z + v.w*v.w;
  }
#pragma unroll
  for (int o = 32; o; o >>= 1) ss += __shfl_down(ss, o, 64);
  if (t == 0) P.vn[r] = sqrtf(ss);
}

// ---------------------------------------------------------------------------
// sim body (w = j + 32*i)
// ---------------------------------------------------------------------------
__device__ __forceinline__ void sim_body(const MegaParams& P, int w, int tid,
                                         char* shraw) {
  float* sG  = (float*)shraw;        // 400
  float* sm  = sG + 400;             // 20
  float* red = sm + 20;              // 4
  int j = w & 31, i = w >> 5;
  for (int p = tid; p < 400; p += 256) sG[p] = P.G[i * 400 + p];
  if (tid < 20) sm[tid] = P.wmask[i * 20 + tid];
  __syncthreads();

  float simv = -1e30f;
  if (tid < TP_) {
    const float* ar = P.Amat + ((size_t)j * TP_ + tid) * 640 + i * 20;
    float a[20], p[20];
    float mx = -1e30f;
#pragma unroll
    for (int l = 0; l < 20; ++l) {
      a[l] = ar[l];
      float lg = (sm[l] > 0.5f) ? LAM_ * a[l] : -1e9f;
      p[l] = lg;
      mx = fmaxf(mx, lg);
    }
    float Z = 0.f;
#pragma unroll
    for (int l = 0; l < 20; ++l) { p[l] = __expf(p[l] - mx); Z += p[l]; }
    float invZ = 1.f / Z, num = 0.f;
#pragma unroll
    for (int l = 0; l < 20; ++l) { p[l] *= invZ; num += p[l] * a[l]; }
    float q2 = 0.f;
#pragma unroll
    for (int l = 0; l < 20; ++l) {
      float gi = 0.f;
#pragma unroll
      for (int l2 = 0; l2 < 20; ++l2) gi += sG[l * 20 + l2] * p[l2];
      q2 += p[l] * gi;
    }
    float vnv = fmaxf(P.vn[(size_t)j * TP_ + tid], 1e-8f);
    float vsnv = fmaxf(sqrtf(q2), 1e-8f);
    simv = num / (vnv * vsnv);
    if (i == j) P.out[1 + i * TP_ + tid] = simv;
  }
  float mv = simv;
#pragma unroll
  for (int o = 32; o; o >>= 1) mv = fmaxf(mv, __shfl_down(mv, o, 64));
  if ((tid & 63) == 0) red[tid >> 6] = mv;
  __syncthreads();
  if (tid == 0)
    P.scores[i * 32 + j] = fmaxf(fmaxf(red[0], red[1]), fmaxf(red[2], red[3]));
  __syncthreads();
}

// loss over scores[32][32] with 256 threads
__device__ __forceinline__ void loss_body(const MegaParams& P, int tid, char* shraw) {
  float* red = (float*)shraw;
  const float* s = P.scores;
  float c = 0.f;
  for (int p = tid; p < 1024; p += 256) {
    int i = p >> 5, j = p & 31;
    float sv = s[p];
    if (i != j)
      c += fmaxf(0.f, MARGIN_ + sv - s[i * 32 + i]) +
           fmaxf(0.f, MARGIN_ + sv - s[j * 32 + j]);
  }
#pragma unroll
  for (int o = 32; o; o >>= 1) c += __shfl_down(c, o, 64);
  if ((tid & 63) == 0) red[tid >> 6] = c;
  __syncthreads();
  if (tid == 0) P.out[0] = (red[0] + red[1] + red[2] + red[3]) / 32.f;
}

// ---------------------------------------------------------------------------
// Kernels (13-launch pipeline)
// ---------------------------------------------------------------------------
__global__ __launch_bounds__(256) void prep_g(MegaParams P) {
  prep_body(P, blockIdx.x, threadIdx.x);
}
__global__ __launch_bounds__(256) void stats2c_g(MegaParams P) {
  __shared__ __align__(16) char shraw[8448];
  stats2c_body(P, blockIdx.x, threadIdx.x, shraw);
}
__global__ __launch_bounds__(256) void cast_g(MegaParams P) {
  cast_body(P, blockIdx.x, threadIdx.x);
}
template<int BM, int BN, bool RELU, bool BIAS, bool OUT_BF16, bool PARTIAL, bool STATS>
__global__ __launch_bounds__(256) void gemm_g(
    const unsigned short* xin, const unsigned short* Wr, const float* bias,
    void* out, float* spart, int b_stride, int row_off, int row_t_stride,
    int To, int M, int t_off_out, int ldout, int Ktot, int Kloc) {
  __shared__ __align__(16) char shraw[SHBYTES];
  int lin = blockIdx.x + gridDim.x * (blockIdx.y + gridDim.y * blockIdx.z);
  gemm_stage<BM,BN,RELU,BIAS,OUT_BF16,PARTIAL,STATS>(
      shraw, lin, gridDim.x, gridDim.y, gridDim.z, xin, Wr, bias, out, spart,
      b_stride, row_off, row_t_stride, To, M, t_off_out, ldout, Ktot, Kloc);
}
template<int S>
__global__ __launch_bounds__(256) void red_g(const float* part, const float* bias,
                                             unsigned short* outb,
                                             int M, int To, int t_off_out) {
  red_body<S>(part, bias, outb, M, To, t_off_out, blockIdx.x, threadIdx.x);
}

// pointwise conv + fused stats1 epilogue + LAST-BLOCK stats2 (v2ms)
__global__ __launch_bounds__(256) void pw_g(MegaParams P) {
  __shared__ __align__(16) char shraw[SHBYTES];
  __shared__ unsigned oldc;
  int lin = blockIdx.x + gridDim.x * blockIdx.y;
  gemm_stage<64,64,false,true,false,false,true>(
      shraw, lin, 110, 8, 1, P.vcb, P.Wp, P.pwb, P.v2, P.v2part,
      112128, 0, 512, TP_, 32 * TP_, 0, 512, 512, 512);
  // last-block stats2: deterministic (fixed-order reduction over v2part)
  __threadfence();
  if (threadIdx.x == 0) oldc = atomicAdd(P.cnt_pw, 1u);
  __syncthreads();
  if (oldc == 110u * 8u - 1u) {
    __threadfence();
    float4* sS = (float4*)shraw;
    float4* sQ = sS + 264;
    for (int b2 = 0; b2 < 4; ++b2) {
      __syncthreads();
      stats2_body(P.v2part, P.v2ms, 512, 110, 1.f / 7008.f, b2, threadIdx.x, sS, sQ);
    }
  }
}

__global__ __launch_bounds__(256) void v2norm_g(MegaParams P) {
  v2norm_body(P, blockIdx.x, threadIdx.x);
}

// sim + LAST-BLOCK margin loss
__global__ __launch_bounds__(256) void sim_g(MegaParams P) {
  __shared__ __align__(16) char shraw[1696];
  __shared__ unsigned oldc;
  sim_body(P, blockIdx.x, threadIdx.x, shraw);
  __threadfence();
  if (threadIdx.x == 0) oldc = atomicAdd(P.cnt_sim, 1u);
  __syncthreads();
  if (oldc == 1023u) {
    __threadfence();
    __syncthreads();
    loss_body(P, threadIdx.x, shraw);
  }
}

// ---------------------------------------------------------------------------
extern "C" void kernel_launch(void* const* d_in, const int* in_sizes, int n_in,
                              void* d_out, int out_size, void* d_ws, size_t ws_size,
                              hipStream_t stream) {
  float* ws = (float*)d_ws;

  // ---- workspace layout (float units); R9 layout + 2 counters ----
  float*          W0r    = ws;                       // 1048576
  float*          W1r    = W0r + 1048576;            // 524288
  float*          W2r    = W1r + 524288;             // 524288
  float*          Wpw    = W2r + 524288;             // 131072
  float*          AMvbf  = Wpw + 131072;             // 4485120 (vbf | Amat)
  float*          vcatb  = AMvbf + 4485120;          // 1794048 (bf16 vcat)
  float*          Pbuf   = vcatb + 1794048;          // 8323072 overlay:
  float*          v2     = Pbuf;                     //   3588096
  float*          v2bfp  = v2 + 3588096;             //   1794048
  float*          v2part = v2bfp + 1794048;          //   112640
  float*          v2ms   = v2part + 112640;          //   1024
  float*          vpart  = v2ms + 1024;              //   1048576
  float*          vms    = vpart + 1048576;          //   2048
  float*          wpart  = vms + 2048;               //   81920
  float*          wms    = wpart + 81920;            //   1024 (fits 8323072)
  float*          endPb  = Pbuf + 8323072;
  float*          wbnbp  = endPb;                    // 163840 (bf16 327680)
  float*          G      = wbnbp + 163840;           // 12800
  float*          vn     = G + 12800;                // 7008
  float*          scores = vn + 7008;                // 1024
  float*          cnts   = scores + 1024;            // 2

  MegaParams P;
  P.video = (const float*)d_in[0];
  P.words = (const float*)d_in[1];
  P.wmask = (const float*)d_in[2];
  P.c0w = (const float*)d_in[3];  P.c0b = (const float*)d_in[4];
  P.c1w = (const float*)d_in[5];  P.c1b = (const float*)d_in[6];
  P.c2w = (const float*)d_in[7];  P.c2b = (const float*)d_in[8];
  P.pww = (const float*)d_in[9];  P.pwb = (const float*)d_in[10];
  P.out = (float*)d_out;
  P.W0 = (unsigned short*)W0r;  P.W1 = (unsigned short*)W1r;
  P.W2 = (unsigned short*)W2r;  P.Wp = (unsigned short*)Wpw;
  P.vbf = (unsigned short*)AMvbf;
  P.vcb = (unsigned short*)vcatb;
  P.v2bf = (unsigned short*)v2bfp;
  P.wbnb = (unsigned short*)wbnbp;
  P.Amat = AMvbf;   P.Pbuf = Pbuf;   P.v2 = v2;
  P.v2part = v2part; P.v2ms = v2ms;  P.vpart = vpart; P.vms = vms;
  P.wpart = wpart;  P.wms = wms;     P.G = G; P.vn = vn; P.scores = scores;
  P.cnt_pw = (unsigned*)cnts;  P.cnt_sim = (unsigned*)cnts + 1;

  // 1: weight reorder + video/words stats1 (+ counter zeroing)
  prep_g<<<4904, 256, 0, stream>>>(P);
  // 2: video + words stats2
  stats2c_g<<<12, 256, 0, stream>>>(P);
  // 3: video BN cast + words BN->bf16 + Gram
  cast_g<<<8224, 256, 0, stream>>>(P);
  // 4/5: conv0 (64x128, K 4x1024) + reduce
  gemm_g<64,128,false,false,false,true,false><<<dim3(64, 4, 4), 256, 0, stream>>>(
      P.vbf, P.W0, nullptr, P.Pbuf, nullptr, 262144, 0, 2048, T0_, 32 * T0_, 0, 512, 4096, 1024);
  red_g<4><<<2032, 256, 0, stream>>>(P.Pbuf, P.c0b, P.vcb, 32 * T0_, T0_, 0);
  // 6/7: conv1 (64x128, K 8x256) + reduce
  gemm_g<64,128,false,false,false,true,false><<<dim3(31, 4, 8), 256, 0, stream>>>(
      P.vcb, P.W1, nullptr, P.Pbuf, nullptr, 112128, 0, 1024, T1_, 32 * T1_, 0, 512, 2048, 256);
  red_g<8><<<992, 256, 0, stream>>>(P.Pbuf, P.c1b, P.vcb, 32 * T1_, T1_, T0_);
  // 8/9: conv2 (64x64, K 8x256) + reduce
  gemm_g<64,64,false,false,false,true,false><<<dim3(15, 8, 8), 256, 0, stream>>>(
      P.vcb, P.W2, nullptr, P.Pbuf, nullptr, 112128, 65024, 1024, T2_, 32 * T2_, 0, 512, 2048, 256);
  red_g<8><<<480, 256, 0, stream>>>(P.Pbuf, P.c2b, P.vcb, 32 * T2_, T2_, T0_ + T1_);
  // 10: pointwise conv + fused stats1 + last-block stats2 (v2ms)
  pw_g<<<dim3(110, 8), 256, 0, stream>>>(P);
  // 11: v2 BN apply + bf16 + row norms
  v2norm_g<<<1752, 256, 0, stream>>>(P);
  // 12: attention A = v.w  (M=7008, N=640, K=512)
  gemm_g<64,64,false,false,false,false,false><<<dim3(110, 10), 256, 0, stream>>>(
      P.v2bf, P.wbnb, nullptr, P.Amat, nullptr, 112128, 0, 512, TP_, 32 * TP_, 0, 640, 512, 512);
  // 13: sim / scores / positive map + last-block margin loss
  sim_g<<<1024, 256, 0, stream>>>(P);
}

// Round 12
// 235.939 us; speedup vs baseline: 12.7870x; 1.6457x over previous
//
#include <hip/hip_runtime.h>
#include <math.h>

// Problem constants
#define B_   32
#define T_   256
#define DV_  1024
#define DJ_  512
#define L_   20
#define T0_  127
#define T1_  62
#define T2_  30
#define TP_  219          // 127+62+30
#define LAM_ 4.0f
#define MARGIN_ 0.1f
#define SHBYTES 25600     // 24KB gemm dbuf + 1KB wred

typedef __attribute__((ext_vector_type(8))) short short8;
typedef __attribute__((ext_vector_type(4))) float f32x4;

static __device__ __forceinline__ unsigned short f2bf(float f) {
  union { float f; unsigned u; } v; v.f = f;
  unsigned r = v.u + 0x7fff + ((v.u >> 16) & 1);   // round-to-nearest-even
  return (unsigned short)(r >> 16);
}

struct ushort4_t { unsigned short x, y, z, w; };

#define GLOAD_LDS16(gp, lp)                                                      \
  __builtin_amdgcn_global_load_lds(                                              \
      (const __attribute__((address_space(1))) void*)(gp),                       \
      (__attribute__((address_space(3))) void*)(lp), 16, 0, 0)

// ---------------------------------------------------------------------------
struct MegaParams {
  const float *video, *words, *wmask;
  const float *c0w, *c0b, *c1w, *c1b, *c2w, *c2b, *pww, *pwb;
  float* out;
  unsigned short *W0, *W1, *W2, *Wp, *vbf, *vcb, *v2bf, *wbnb;
  float *Amat, *Pbuf, *v2, *v2part, *v2ms, *vpart, *vms, *wpart, *wms,
        *G, *vn, *scores;
};

// ---------------------------------------------------------------------------
// BatchNorm stats bodies (deterministic two-stage).  [HW-verified R9/R10]
// ---------------------------------------------------------------------------
__device__ __forceinline__ void stats1_body(const float* __restrict__ x,
                                            float* __restrict__ part,
                                            int C, int rows, int rpg, int cpgShift,
                                            int bid, int tid) {
  int cpg  = 1 << cpgShift;                 // C/4
  int c4   = tid & (cpg - 1);
  int rsub = tid >> cpgShift;
  int nsub = 256 >> cpgShift;
  int r0 = bid * rpg + rsub;
  int r1 = min(bid * rpg + rpg, rows);
  float4 s = {0.f,0.f,0.f,0.f}, q = {0.f,0.f,0.f,0.f};
  for (int r = r0; r < r1; r += nsub) {
    float4 v = *reinterpret_cast<const float4*>(&x[(size_t)r * C + c4 * 4]);
    s.x += v.x; s.y += v.y; s.z += v.z; s.w += v.w;
    q.x += v.x*v.x; q.y += v.y*v.y; q.z += v.z*v.z; q.w += v.w*v.w;
  }
  float* ps = part + ((size_t)bid * nsub + rsub) * 2 * C;
  reinterpret_cast<float4*>(ps)[c4] = s;
  reinterpret_cast<float4*>(ps + C)[c4] = q;
}

__device__ __forceinline__ void stats2_body(const float* __restrict__ part,
                                            float* __restrict__ ms,
                                            int C, int ng, float inv_n,
                                            int bid, int tid,
                                            float4* sS, float4* sQ) {
  int c4l = tid & 31;
  int gs  = tid >> 5;
  int c4  = bid * 32 + c4l;                 // float4 channel index
  float4 s = {0.f,0.f,0.f,0.f}, q = {0.f,0.f,0.f,0.f};
  for (int g = gs; g < ng; g += 8) {
    const float4* ps = reinterpret_cast<const float4*>(part + (size_t)g * 2 * C);
    float4 a = ps[c4];
    float4 b = ps[(C >> 2) + c4];
    s.x += a.x; s.y += a.y; s.z += a.z; s.w += a.w;
    q.x += b.x; q.y += b.y; q.z += b.z; q.w += b.w;
  }
  sS[gs * 33 + c4l] = s; sQ[gs * 33 + c4l] = q;
  __syncthreads();
  if (gs == 0) {
    float4 S = sS[c4l], Q = sQ[c4l];
#pragma unroll
    for (int k = 1; k < 8; ++k) {
      float4 a = sS[k * 33 + c4l], b = sQ[k * 33 + c4l];
      S.x += a.x; S.y += a.y; S.z += a.z; S.w += a.w;
      Q.x += b.x; Q.y += b.y; Q.z += b.z; Q.w += b.w;
    }
    int c = c4 * 4;
    float m0 = S.x * inv_n, m1 = S.y * inv_n, m2 = S.z * inv_n, m3 = S.w * inv_n;
    ms[c+0] = m0; ms[C+c+0] = rsqrtf(Q.x * inv_n - m0*m0 + 1e-5f);
    ms[c+1] = m1; ms[C+c+1] = rsqrtf(Q.y * inv_n - m1*m1 + 1e-5f);
    ms[c+2] = m2; ms[C+c+2] = rsqrtf(Q.z * inv_n - m2*m2 + 1e-5f);
    ms[c+3] = m3; ms[C+c+3] = rsqrtf(Q.w * inv_n - m3*m3 + 1e-5f);
  }
}

// ---------------------------------------------------------------------------
// prep: weight reorder+cast | video stats1 | words stats1.
// ---------------------------------------------------------------------------
__device__ __forceinline__ void prep_body(const MegaParams& P, int bid, int tid) {
  if (bid < 2048) {            // conv0: 512*1024 (co,ci) pairs
    int idx = bid * 256 + tid;
    int co = idx >> 10, ci = idx & 1023;
    float4 w = *reinterpret_cast<const float4*>(P.c0w + (size_t)idx * 4);
    unsigned short* d = P.W0 + (size_t)co * 4096 + ci;
    d[0] = f2bf(w.x); d[1024] = f2bf(w.y); d[2048] = f2bf(w.z); d[3072] = f2bf(w.w);
  } else if (bid < 3072) {     // conv1
    int idx = (bid - 2048) * 256 + tid;
    int co = idx >> 9, ci = idx & 511;
    float4 w = *reinterpret_cast<const float4*>(P.c1w + (size_t)idx * 4);
    unsigned short* d = P.W1 + (size_t)co * 2048 + ci;
    d[0] = f2bf(w.x); d[512] = f2bf(w.y); d[1024] = f2bf(w.z); d[1536] = f2bf(w.w);
  } else if (bid < 4096) {     // conv2
    int idx = (bid - 3072) * 256 + tid;
    int co = idx >> 9, ci = idx & 511;
    float4 w = *reinterpret_cast<const float4*>(P.c2w + (size_t)idx * 4);
    unsigned short* d = P.W2 + (size_t)co * 2048 + ci;
    d[0] = f2bf(w.x); d[512] = f2bf(w.y); d[1024] = f2bf(w.z); d[1536] = f2bf(w.w);
  } else if (bid < 4352) {     // pw identity cast
    int idx = (bid - 4096) * 256 + tid;
    float4 v = *reinterpret_cast<const float4*>(P.pww + (size_t)idx * 4);
    ushort4_t h = { f2bf(v.x), f2bf(v.y), f2bf(v.z), f2bf(v.w) };
    reinterpret_cast<ushort4_t*>(P.Wp)[idx] = h;
  } else if (bid < 4864) {     // video stats1
    stats1_body(P.video, P.vpart, 1024, 8192, 16, 8, bid - 4352, tid);
  } else {                     // words stats1
    stats1_body(P.words, P.wpart, 512, 640, 16, 7, bid - 4864, tid);
  }
}

__device__ __forceinline__ void stats2c_body(const MegaParams& P, int bid, int tid,
                                             char* shraw) {
  float4* sS = (float4*)shraw;
  float4* sQ = sS + 264;
  if (bid < 8) stats2_body(P.vpart, P.vms, 1024, 512, 1.f / 8192.f, bid, tid, sS, sQ);
  else         stats2_body(P.wpart, P.wms, 512,  80,  1.f / 640.f,  bid - 8, tid, sS, sQ);
}

// ---------------------------------------------------------------------------
// cast: video BN apply+cast (0..8191) | words BN->bf16 + Gram fp32 (8192..8223)
// ---------------------------------------------------------------------------
__device__ __forceinline__ void cast_body(const MegaParams& P, int w, int tid) {
  if (w < 8192) {
    int i4 = w * 256 + tid;
    float4 v = reinterpret_cast<const float4*>(P.video)[i4];
    int c = (i4 & 255) * 4;
    v.x = (v.x - P.vms[c+0]) * P.vms[1024+c+0];
    v.y = (v.y - P.vms[c+1]) * P.vms[1024+c+1];
    v.z = (v.z - P.vms[c+2]) * P.vms[1024+c+2];
    v.w = (v.w - P.vms[c+3]) * P.vms[1024+c+3];
    ushort4_t h = { f2bf(v.x), f2bf(v.y), f2bf(v.z), f2bf(v.w) };
    reinterpret_cast<ushort4_t*>(P.vbf)[i4] = h;
  } else {
    int i = w - 8192;                        // sentence
    const float* wr = P.words + (size_t)i * L_ * DJ_;
    unsigned short* wb = P.wbnb + (size_t)i * L_ * DJ_;
    for (int idx = tid; idx < L_ * DJ_; idx += 256) {
      int d = idx & 511;
      wb[idx] = f2bf((wr[idx] - P.wms[d]) * P.wms[DJ_ + d]);
    }
    for (int p = tid; p < L_ * L_; p += 256) {
      int l = p / L_, l2 = p % L_;
      const float* a = wr + l * DJ_;
      const float* b = wr + l2 * DJ_;
      float acc = 0.f;
      for (int d = 0; d < DJ_; ++d) {
        float av = (a[d] - P.wms[d]) * P.wms[DJ_ + d];
        float bv = (b[d] - P.wms[d]) * P.wms[DJ_ + d];
        acc += av * bv;
      }
      P.G[i * 400 + p] = acc;
    }
  }
}

// ---------------------------------------------------------------------------
// MFMA bf16 GEMM stage.  [HW-verified R9/R10]
// ---------------------------------------------------------------------------
template<int BM, int BN, bool RELU, bool BIAS, bool OUT_BF16, bool PARTIAL, bool STATS>
__device__ __forceinline__ void gemm_stage(
    char* shraw, int lin, int gx, int gy, int gz,
    const unsigned short* __restrict__ xin, const unsigned short* __restrict__ Wr,
    const float* __restrict__ bias, void* __restrict__ out, float* __restrict__ spart,
    int b_stride, int row_off, int row_t_stride,
    int To, int M, int t_off_out, int ldout, int Ktot, int Kloc)
{
  constexpr int AI = BM / 64, BI = BN / 64;     // staging issues per side
  constexpr int FM = BM / 32, FN = BN / 32;     // frags per wave
  short* As   = (short*)shraw;                        // 2*BM*32 shorts
  short* Bs   = (short*)(shraw + (size_t)2 * BM * 32 * 2);
  float* wred = (float*)(shraw + 24576);

  const int tid  = threadIdx.x;
  const int lane = tid & 63;
  const int wv   = tid >> 6;
  const int wr   = wv >> 1;
  const int wc   = wv & 1;

  // bijective XCD swizzle (m204)
  const int nwg = gx * gy * gz;
  const int q = nwg >> 3, r = nwg & 7;
  const int xcd = lin & 7, sub = lin >> 3;
  const int work = (xcd < r ? xcd * (q + 1) : r * (q + 1) + (xcd - r) * q) + sub;
  const int bx = work % gx;
  const int by = (work / gx) % gy;
  const int bz = work / (gx * gy);

  const int mbase = bx * BM;
  const int nbase = by * BN;
  const int kstart = PARTIAL ? bz * Kloc : 0;

  const int srow = tid >> 2;                       // 0..63
  const int sb   = (((tid & 3) ^ ((srow ^ (srow >> 2)) & 3))) * 8;
  const unsigned short* agp[AI];
  const unsigned short* bgp[BI];
#pragma unroll
  for (int i = 0; i < AI; ++i) {
    int ma = min(mbase + i * 64 + srow, M - 1);
    int b0 = ma / To, t0 = ma % To;
    agp[i] = xin + (size_t)b0 * b_stride + row_off
             + (size_t)t0 * row_t_stride + sb + kstart;
  }
#pragma unroll
  for (int i = 0; i < BI; ++i)
    bgp[i] = Wr + (size_t)(nbase + i * 64 + srow) * Ktot + sb + kstart;

  f32x4 acc[FM][FN] = {};
  const int nsteps = Kloc >> 5;

#define STAGE_(buf, k0)                                                        \
  do {                                                                         \
    _Pragma("unroll")                                                          \
    for (int i = 0; i < AI; ++i)                                               \
      GLOAD_LDS16(agp[i] + (k0), &As[(buf) * (BM * 32) + i * 2048 + wv * 512]);\
    _Pragma("unroll")                                                          \
    for (int i = 0; i < BI; ++i)                                               \
      GLOAD_LDS16(bgp[i] + (k0), &Bs[(buf) * (BN * 32) + i * 2048 + wv * 512]);\
  } while (0)

  STAGE_(0, 0);
  __syncthreads();

  const int l15   = lane & 15;
  const int rsw   = (l15 ^ (l15 >> 2)) & 3;
  const int chunk = ((lane >> 4) ^ rsw) * 8;
  const int a_off = (wr * (BM / 2) + l15) * 32 + chunk;
  const int b_off = (wc * (BN / 2) + l15) * 32 + chunk;

  for (int s = 0; s < nsteps; ++s) {
    const int nb = s & 1;
    if (s + 1 < nsteps) STAGE_(nb ^ 1, (s + 1) * 32);

    const short* Ab = &As[nb * (BM * 32) + a_off];
    const short* Bb = &Bs[nb * (BN * 32) + b_off];
    short8 af[FM], bf[FN];
#pragma unroll
    for (int f = 0; f < FM; ++f)
      af[f] = *reinterpret_cast<const short8*>(Ab + f * 512);
#pragma unroll
    for (int f = 0; f < FN; ++f)
      bf[f] = *reinterpret_cast<const short8*>(Bb + f * 512);
#pragma unroll
    for (int fm = 0; fm < FM; ++fm)
#pragma unroll
      for (int fn = 0; fn < FN; ++fn)
        acc[fm][fn] = __builtin_amdgcn_mfma_f32_16x16x32_bf16(af[fm], bf[fn], acc[fm][fn], 0, 0, 0);

    __syncthreads();
  }
#undef STAGE_

  // epilogue: C/D map col=lane&15, row=4*(lane>>4)+reg
  const int cl = lane & 15, rh = lane >> 4;
  float ls[FN], lq[FN];
#pragma unroll
  for (int f = 0; f < FN; ++f) { ls[f] = 0.f; lq[f] = 0.f; }
#pragma unroll
  for (int fm = 0; fm < FM; ++fm) {
#pragma unroll
    for (int fn = 0; fn < FN; ++fn) {
      int col = nbase + wc * (BN / 2) + fn * 16 + cl;
      float bv = BIAS ? bias[col] : 0.f;
      f32x4 v = acc[fm][fn];
#pragma unroll
      for (int rr = 0; rr < 4; ++rr) {
        int m = mbase + wr * (BM / 2) + fm * 16 + rh * 4 + rr;
        if (m < M) {
          if (PARTIAL) {
            float* pout = (float*)out + (size_t)bz * ((size_t)M * ldout);
            pout[(size_t)m * ldout + col] = v[rr];
          } else {
            int b = m / To, to = m % To;
            float x = v[rr] + bv;
            if (RELU) x = fmaxf(x, 0.f);
            size_t oi = ((size_t)b * TP_ + t_off_out + to) * (size_t)ldout + col;
            if (OUT_BF16) ((unsigned short*)out)[oi] = f2bf(x);
            else          ((float*)out)[oi] = x;
            if (STATS) { ls[fn] += x; lq[fn] += x * x; }
          }
        }
      }
    }
  }

  if (STATS) {   // deterministic per-block column stats (BM=BN=64 path)
#pragma unroll
    for (int fn = 0; fn < FN; ++fn) {
      float s = ls[fn], qq = lq[fn];
      s  += __shfl_xor(s, 16, 64);  qq += __shfl_xor(qq, 16, 64);
      s  += __shfl_xor(s, 32, 64);  qq += __shfl_xor(qq, 32, 64);
      if (rh == 0) {
        wred[wv * 64 + fn * 16 + cl]      = s;
        wred[wv * 64 + 32 + fn * 16 + cl] = qq;
      }
    }
    __syncthreads();
    if (tid < 64) {
      int wc2 = tid >> 5, cl2 = tid & 31;
      float s  = wred[wc2 * 64 + cl2]      + wred[(wc2 + 2) * 64 + cl2];
      float qq = wred[wc2 * 64 + 32 + cl2] + wred[(wc2 + 2) * 64 + 32 + cl2];
      int chan = nbase + wc2 * 32 + cl2;
      spart[(size_t)bx * 1024 + chan]       = s;
      spart[(size_t)bx * 1024 + 512 + chan] = qq;
    }
    __syncthreads();
  }
}

// ---------------------------------------------------------------------------
// K-split reduce body
// ---------------------------------------------------------------------------
template<int S>
__device__ __forceinline__ void red_body(const float* __restrict__ part,
                                         const float* __restrict__ bias,
                                         unsigned short* __restrict__ outb,
                                         int M, int To, int t_off_out,
                                         int w, int tid) {
  int idx = w * 256 + tid;
  int m = idx >> 7, n4 = idx & 127;
  if (m >= M) return;
  size_t off = (size_t)m * 512 + n4 * 4;
  float4 a = *reinterpret_cast<const float4*>(part + off);
#pragma unroll
  for (int s = 1; s < S; ++s) {
    float4 b = *reinterpret_cast<const float4*>(part + (size_t)s * M * 512 + off);
    a.x += b.x; a.y += b.y; a.z += b.z; a.w += b.w;
  }
  float4 bv = *reinterpret_cast<const float4*>(bias + n4 * 4);
  a.x = fmaxf(a.x + bv.x, 0.f);
  a.y = fmaxf(a.y + bv.y, 0.f);
  a.z = fmaxf(a.z + bv.z, 0.f);
  a.w = fmaxf(a.w + bv.w, 0.f);
  int b_ = m / To, to = m % To;
  ushort4_t h = { f2bf(a.x), f2bf(a.y), f2bf(a.z), f2bf(a.w) };
  reinterpret_cast<ushort4_t*>(outb + ((size_t)b_ * TP_ + t_off_out + to) * 512)[n4] = h;
}

// ---------------------------------------------------------------------------
// v2 normalize + bf16 + row norm: 4 rows per 256-thread block
// ---------------------------------------------------------------------------
__device__ __forceinline__ void v2norm_body(const MegaParams& P, int w, int tid) {
  int r = w * 4 + (tid >> 6);
  int t = tid & 63;
  float* row = P.v2 + (size_t)r * DJ_;
  unsigned short* brow = P.v2bf + (size_t)r * DJ_;
  const float* ms = P.v2ms;
  float ss = 0.f;
#pragma unroll
  for (int h = 0; h < 2; ++h) {
    int c4 = t + h * 64;
    float4 v = reinterpret_cast<float4*>(row)[c4];
    int c = c4 * 4;
    v.x = (v.x - ms[c+0]) * ms[DJ_+c+0];
    v.y = (v.y - ms[c+1]) * ms[DJ_+c+1];
    v.z = (v.z - ms[c+2]) * ms[DJ_+c+2];
    v.w = (v.w - ms[c+3]) * ms[DJ_+c+3];
    reinterpret_cast<float4*>(row)[c4] = v;
    ushort4_t h4 = { f2bf(v.x), f2bf(v.y), f2bf(v.z), f2bf(v.w) };
    reinterpret_cast<ushort4_t*>(brow)[c4] = h4;
    ss += v.x*v.x + v.y*v.y + v.z*v.z + v.w*v.w;
  }
#pragma unroll
  for (int o = 32; o; o >>= 1) ss += __shfl_down(ss, o, 64);
  if (t == 0) P.vn[r] = sqrtf(ss);
}

// ---------------------------------------------------------------------------
// sim body (w = j + 32*i)
// ---------------------------------------------------------------------------
__device__ __forceinline__ void sim_body(const MegaParams& P, int w, int tid,
                                         char* shraw) {
  float* sG  = (float*)shraw;        // 400
  float* sm  = sG + 400;             // 20
  float* red = sm + 20;              // 4
  int j = w & 31, i = w >> 5;
  for (int p = tid; p < 400; p += 256) sG[p] = P.G[i * 400 + p];
  if (tid < 20) sm[tid] = P.wmask[i * 20 + tid];
  __syncthreads();

  float simv = -1e30f;
  if (tid < TP_) {
    const float* ar = P.Amat + ((size_t)j * TP_ + tid) * 640 + i * 20;
    float a[20], p[20];
    float mx = -1e30f;
#pragma unroll
    for (int l = 0; l < 20; ++l) {
      a[l] = ar[l];
      float lg = (sm[l] > 0.5f) ? LAM_ * a[l] : -1e9f;
      p[l] = lg;
      mx = fmaxf(mx, lg);
    }
    float Z = 0.f;
#pragma unroll
    for (int l = 0; l < 20; ++l) { p[l] = __expf(p[l] - mx); Z += p[l]; }
    float invZ = 1.f / Z, num = 0.f;
#pragma unroll
    for (int l = 0; l < 20; ++l) { p[l] *= invZ; num += p[l] * a[l]; }
    float q2 = 0.f;
#pragma unroll
    for (int l = 0; l < 20; ++l) {
      float gi = 0.f;
#pragma unroll
      for (int l2 = 0; l2 < 20; ++l2) gi += sG[l * 20 + l2] * p[l2];
      q2 += p[l] * gi;
    }
    float vnv = fmaxf(P.vn[(size_t)j * TP_ + tid], 1e-8f);
    float vsnv = fmaxf(sqrtf(q2), 1e-8f);
    simv = num / (vnv * vsnv);
    if (i == j) P.out[1 + i * TP_ + tid] = simv;
  }
  float mv = simv;
#pragma unroll
  for (int o = 32; o; o >>= 1) mv = fmaxf(mv, __shfl_down(mv, o, 64));
  if ((tid & 63) == 0) red[tid >> 6] = mv;
  __syncthreads();
  if (tid == 0)
    P.scores[i * 32 + j] = fmaxf(fmaxf(red[0], red[1]), fmaxf(red[2], red[3]));
}

// loss over scores[32][32] with 256 threads
__device__ __forceinline__ void loss_body(const MegaParams& P, int tid, char* shraw) {
  float* red = (float*)shraw;
  const float* s = P.scores;
  float c = 0.f;
  for (int p = tid; p < 1024; p += 256) {
    int i = p >> 5, j = p & 31;
    float sv = s[p];
    if (i != j)
      c += fmaxf(0.f, MARGIN_ + sv - s[i * 32 + i]) +
           fmaxf(0.f, MARGIN_ + sv - s[j * 32 + j]);
  }
#pragma unroll
  for (int o = 32; o; o >>= 1) c += __shfl_down(c, o, 64);
  if ((tid & 63) == 0) red[tid >> 6] = c;
  __syncthreads();
  if (tid == 0) P.out[0] = (red[0] + red[1] + red[2] + red[3]) / 32.f;
}

// ---------------------------------------------------------------------------
// Kernels (15-launch pipeline, R9 structure)
// ---------------------------------------------------------------------------
__global__ __launch_bounds__(256) void prep_g(MegaParams P) {
  prep_body(P, blockIdx.x, threadIdx.x);
}
__global__ __launch_bounds__(256) void stats2c_g(MegaParams P) {
  __shared__ __align__(16) char shraw[8448];
  stats2c_body(P, blockIdx.x, threadIdx.x, shraw);
}
__global__ __launch_bounds__(256) void cast_g(MegaParams P) {
  cast_body(P, blockIdx.x, threadIdx.x);
}
template<int BM, int BN, bool RELU, bool BIAS, bool OUT_BF16, bool PARTIAL, bool STATS>
__global__ __launch_bounds__(256) void gemm_g(
    const unsigned short* xin, const unsigned short* Wr, const float* bias,
    void* out, float* spart, int b_stride, int row_off, int row_t_stride,
    int To, int M, int t_off_out, int ldout, int Ktot, int Kloc) {
  __shared__ __align__(16) char shraw[SHBYTES];
  int lin = blockIdx.x + gridDim.x * (blockIdx.y + gridDim.y * blockIdx.z);
  gemm_stage<BM,BN,RELU,BIAS,OUT_BF16,PARTIAL,STATS>(
      shraw, lin, gridDim.x, gridDim.y, gridDim.z, xin, Wr, bias, out, spart,
      b_stride, row_off, row_t_stride, To, M, t_off_out, ldout, Ktot, Kloc);
}
template<int S>
__global__ __launch_bounds__(256) void red_g(const float* part, const float* bias,
                                             unsigned short* outb,
                                             int M, int To, int t_off_out) {
  red_body<S>(part, bias, outb, M, To, t_off_out, blockIdx.x, threadIdx.x);
}
__global__ __launch_bounds__(256) void stats2v_g(MegaParams P) {
  __shared__ __align__(16) char shraw[8448];
  stats2_body(P.v2part, P.v2ms, 512, 110, 1.f / 7008.f, blockIdx.x, threadIdx.x,
              (float4*)shraw, (float4*)shraw + 264);
}
__global__ __launch_bounds__(256) void v2norm_g(MegaParams P) {
  v2norm_body(P, blockIdx.x, threadIdx.x);
}
__global__ __launch_bounds__(256) void sim_g(MegaParams P) {
  __shared__ __align__(16) char shraw[1696];
  sim_body(P, blockIdx.x, threadIdx.x, shraw);
}
__global__ __launch_bounds__(256) void loss_g(MegaParams P) {
  __shared__ __align__(16) char shraw[64];
  loss_body(P, threadIdx.x, shraw);
}

// ---------------------------------------------------------------------------
extern "C" void kernel_launch(void* const* d_in, const int* in_sizes, int n_in,
                              void* d_out, int out_size, void* d_ws, size_t ws_size,
                              hipStream_t stream) {
  float* ws = (float*)d_ws;

  // ---- workspace layout (float units); R9 layout ----
  float*          W0r    = ws;                       // 1048576
  float*          W1r    = W0r + 1048576;            // 524288
  float*          W2r    = W1r + 524288;             // 524288
  float*          Wpw    = W2r + 524288;             // 131072
  float*          AMvbf  = Wpw + 131072;             // 4485120 (vbf | Amat)
  float*          vcatb  = AMvbf + 4485120;          // 1794048 (bf16 vcat)
  float*          Pbuf   = vcatb + 1794048;          // 8323072 overlay:
  float*          v2     = Pbuf;                     //   3588096
  float*          v2bfp  = v2 + 3588096;             //   1794048
  float*          v2part = v2bfp + 1794048;          //   112640
  float*          v2ms   = v2part + 112640;          //   1024
  float*          vpart  = v2ms + 1024;              //   1048576
  float*          vms    = vpart + 1048576;          //   2048
  float*          wpart  = vms + 2048;               //   81920
  float*          wms    = wpart + 81920;            //   1024 (fits 8323072)
  float*          endPb  = Pbuf + 8323072;
  float*          wbnbp  = endPb;                    // 163840 (bf16 327680)
  float*          G      = wbnbp + 163840;           // 12800
  float*          vn     = G + 12800;                // 7008
  float*          scores = vn + 7008;                // 1024

  MegaParams P;
  P.video = (const float*)d_in[0];
  P.words = (const float*)d_in[1];
  P.wmask = (const float*)d_in[2];
  P.c0w = (const float*)d_in[3];  P.c0b = (const float*)d_in[4];
  P.c1w = (const float*)d_in[5];  P.c1b = (const float*)d_in[6];
  P.c2w = (const float*)d_in[7];  P.c2b = (const float*)d_in[8];
  P.pww = (const float*)d_in[9];  P.pwb = (const float*)d_in[10];
  P.out = (float*)d_out;
  P.W0 = (unsigned short*)W0r;  P.W1 = (unsigned short*)W1r;
  P.W2 = (unsigned short*)W2r;  P.Wp = (unsigned short*)Wpw;
  P.vbf = (unsigned short*)AMvbf;
  P.vcb = (unsigned short*)vcatb;
  P.v2bf = (unsigned short*)v2bfp;
  P.wbnb = (unsigned short*)wbnbp;
  P.Amat = AMvbf;   P.Pbuf = Pbuf;   P.v2 = v2;
  P.v2part = v2part; P.v2ms = v2ms;  P.vpart = vpart; P.vms = vms;
  P.wpart = wpart;  P.wms = wms;     P.G = G; P.vn = vn; P.scores = scores;

  // 1: weight reorder + video/words stats1
  prep_g<<<4904, 256, 0, stream>>>(P);
  // 2: video + words stats2
  stats2c_g<<<12, 256, 0, stream>>>(P);
  // 3: video BN cast + words BN->bf16 + Gram
  cast_g<<<8224, 256, 0, stream>>>(P);
  // 4/5: conv0 (64x128, K 4x1024) + reduce
  gemm_g<64,128,false,false,false,true,false><<<dim3(64, 4, 4), 256, 0, stream>>>(
      P.vbf, P.W0, nullptr, P.Pbuf, nullptr, 262144, 0, 2048, T0_, 32 * T0_, 0, 512, 4096, 1024);
  red_g<4><<<2032, 256, 0, stream>>>(P.Pbuf, P.c0b, P.vcb, 32 * T0_, T0_, 0);
  // 6/7: conv1 (64x128, K 8x256) + reduce
  gemm_g<64,128,false,false,false,true,false><<<dim3(31, 4, 8), 256, 0, stream>>>(
      P.vcb, P.W1, nullptr, P.Pbuf, nullptr, 112128, 0, 1024, T1_, 32 * T1_, 0, 512, 2048, 256);
  red_g<8><<<992, 256, 0, stream>>>(P.Pbuf, P.c1b, P.vcb, 32 * T1_, T1_, T0_);
  // 8/9: conv2 (64x64, K 8x256) + reduce
  gemm_g<64,64,false,false,false,true,false><<<dim3(15, 8, 8), 256, 0, stream>>>(
      P.vcb, P.W2, nullptr, P.Pbuf, nullptr, 112128, 65024, 1024, T2_, 32 * T2_, 0, 512, 2048, 256);
  red_g<8><<<480, 256, 0, stream>>>(P.Pbuf, P.c2b, P.vcb, 32 * T2_, T2_, T0_ + T1_);
  // 10: pointwise conv + fused stats1 epilogue
  gemm_g<64,64,false,true,false,false,true><<<dim3(110, 8), 256, 0, stream>>>(
      P.vcb, P.Wp, P.pwb, P.v2, P.v2part, 112128, 0, 512, TP_, 32 * TP_, 0, 512, 512, 512);
  // 11: v2 stats2
  stats2v_g<<<4, 256, 0, stream>>>(P);
  // 12: v2 BN apply + bf16 + row norms
  v2norm_g<<<1752, 256, 0, stream>>>(P);
  // 13: attention A = v.w  (M=7008, N=640, K=512)
  gemm_g<64,64,false,false,false,false,false><<<dim3(110, 10), 256, 0, stream>>>(
      P.v2bf, P.wbnb, nullptr, P.Amat, nullptr, 112128, 0, 512, TP_, 32 * TP_, 0, 640, 512, 512);
  // 14: sim / scores / positive map
  sim_g<<<1024, 256, 0, stream>>>(P);
  // 15: loss
  loss_g<<<1, 256, 0, stream>>>(P);
}

// Round 13
// 203.985 us; speedup vs baseline: 14.7901x; 1.1566x over previous
//
#include <hip/hip_runtime.h>
#include <math.h>

// Problem constants
#define B_   32
#define T_   256
#define DV_  1024
#define DJ_  512
#define L_   20
#define T0_  127
#define T1_  62
#define T2_  30
#define TP_  219          // 127+62+30
#define LAM_ 4.0f
#define MARGIN_ 0.1f
#define SHBYTES 25600     // 24KB gemm dbuf + 1KB wred

typedef __attribute__((ext_vector_type(8))) short short8;
typedef __attribute__((ext_vector_type(4))) float f32x4;

static __device__ __forceinline__ unsigned short f2bf(float f) {
  union { float f; unsigned u; } v; v.f = f;
  unsigned r = v.u + 0x7fff + ((v.u >> 16) & 1);   // round-to-nearest-even
  return (unsigned short)(r >> 16);
}

struct ushort4_t { unsigned short x, y, z, w; };

#define GLOAD_LDS16(gp, lp)                                                      \
  __builtin_amdgcn_global_load_lds(                                              \
      (const __attribute__((address_space(1))) void*)(gp),                       \
      (__attribute__((address_space(3))) void*)(lp), 16, 0, 0)

// ---------------------------------------------------------------------------
struct MegaParams {
  const float *video, *words, *wmask;
  const float *c0w, *c0b, *c1w, *c1b, *c2w, *c2b, *pww, *pwb;
  float* out;
  unsigned short *W0, *W1, *W2, *Wp, *vbf, *vcb, *v2bf, *wbnb;
  float *Amat, *Pbuf, *v2, *v2part, *v2ms, *vpart, *vms, *wpart, *wms,
        *G, *vn, *scores;
};

// ---------------------------------------------------------------------------
// BatchNorm stats bodies (deterministic two-stage).  [HW-verified R9/R10]
// ---------------------------------------------------------------------------
__device__ __forceinline__ void stats1_body(const float* __restrict__ x,
                                            float* __restrict__ part,
                                            int C, int rows, int rpg, int cpgShift,
                                            int bid, int tid) {
  int cpg  = 1 << cpgShift;                 // C/4
  int c4   = tid & (cpg - 1);
  int rsub = tid >> cpgShift;
  int nsub = 256 >> cpgShift;
  int r0 = bid * rpg + rsub;
  int r1 = min(bid * rpg + rpg, rows);
  float4 s = {0.f,0.f,0.f,0.f}, q = {0.f,0.f,0.f,0.f};
  for (int r = r0; r < r1; r += nsub) {
    float4 v = *reinterpret_cast<const float4*>(&x[(size_t)r * C + c4 * 4]);
    s.x += v.x; s.y += v.y; s.z += v.z; s.w += v.w;
    q.x += v.x*v.x; q.y += v.y*v.y; q.z += v.z*v.z; q.w += v.w*v.w;
  }
  float* ps = part + ((size_t)bid * nsub + rsub) * 2 * C;
  reinterpret_cast<float4*>(ps)[c4] = s;
  reinterpret_cast<float4*>(ps + C)[c4] = q;
}

__device__ __forceinline__ void stats2_body(const float* __restrict__ part,
                                            float* __restrict__ ms,
                                            int C, int ng, float inv_n,
                                            int bid, int tid,
                                            float4* sS, float4* sQ) {
  int c4l = tid & 31;
  int gs  = tid >> 5;
  int c4  = bid * 32 + c4l;                 // float4 channel index
  float4 s = {0.f,0.f,0.f,0.f}, q = {0.f,0.f,0.f,0.f};
  for (int g = gs; g < ng; g += 8) {
    const float4* ps = reinterpret_cast<const float4*>(part + (size_t)g * 2 * C);
    float4 a = ps[c4];
    float4 b = ps[(C >> 2) + c4];
    s.x += a.x; s.y += a.y; s.z += a.z; s.w += a.w;
    q.x += b.x; q.y += b.y; q.z += b.z; q.w += b.w;
  }
  sS[gs * 33 + c4l] = s; sQ[gs * 33 + c4l] = q;
  __syncthreads();
  if (gs == 0) {
    float4 S = sS[c4l], Q = sQ[c4l];
#pragma unroll
    for (int k = 1; k < 8; ++k) {
      float4 a = sS[k * 33 + c4l], b = sQ[k * 33 + c4l];
      S.x += a.x; S.y += a.y; S.z += a.z; S.w += a.w;
      Q.x += b.x; Q.y += b.y; Q.z += b.z; Q.w += b.w;
    }
    int c = c4 * 4;
    float m0 = S.x * inv_n, m1 = S.y * inv_n, m2 = S.z * inv_n, m3 = S.w * inv_n;
    ms[c+0] = m0; ms[C+c+0] = rsqrtf(Q.x * inv_n - m0*m0 + 1e-5f);
    ms[c+1] = m1; ms[C+c+1] = rsqrtf(Q.y * inv_n - m1*m1 + 1e-5f);
    ms[c+2] = m2; ms[C+c+2] = rsqrtf(Q.z * inv_n - m2*m2 + 1e-5f);
    ms[c+3] = m3; ms[C+c+3] = rsqrtf(Q.w * inv_n - m3*m3 + 1e-5f);
  }
}

// ---------------------------------------------------------------------------
// prep: weight reorder+cast | video stats1 | words stats1.
// ---------------------------------------------------------------------------
__device__ __forceinline__ void prep_body(const MegaParams& P, int bid, int tid) {
  if (bid < 2048) {            // conv0: 512*1024 (co,ci) pairs
    int idx = bid * 256 + tid;
    int co = idx >> 10, ci = idx & 1023;
    float4 w = *reinterpret_cast<const float4*>(P.c0w + (size_t)idx * 4);
    unsigned short* d = P.W0 + (size_t)co * 4096 + ci;
    d[0] = f2bf(w.x); d[1024] = f2bf(w.y); d[2048] = f2bf(w.z); d[3072] = f2bf(w.w);
  } else if (bid < 3072) {     // conv1
    int idx = (bid - 2048) * 256 + tid;
    int co = idx >> 9, ci = idx & 511;
    float4 w = *reinterpret_cast<const float4*>(P.c1w + (size_t)idx * 4);
    unsigned short* d = P.W1 + (size_t)co * 2048 + ci;
    d[0] = f2bf(w.x); d[512] = f2bf(w.y); d[1024] = f2bf(w.z); d[1536] = f2bf(w.w);
  } else if (bid < 4096) {     // conv2
    int idx = (bid - 3072) * 256 + tid;
    int co = idx >> 9, ci = idx & 511;
    float4 w = *reinterpret_cast<const float4*>(P.c2w + (size_t)idx * 4);
    unsigned short* d = P.W2 + (size_t)co * 2048 + ci;
    d[0] = f2bf(w.x); d[512] = f2bf(w.y); d[1024] = f2bf(w.z); d[1536] = f2bf(w.w);
  } else if (bid < 4352) {     // pw identity cast
    int idx = (bid - 4096) * 256 + tid;
    float4 v = *reinterpret_cast<const float4*>(P.pww + (size_t)idx * 4);
    ushort4_t h = { f2bf(v.x), f2bf(v.y), f2bf(v.z), f2bf(v.w) };
    reinterpret_cast<ushort4_t*>(P.Wp)[idx] = h;
  } else if (bid < 4864) {     // video stats1
    stats1_body(P.video, P.vpart, 1024, 8192, 16, 8, bid - 4352, tid);
  } else {                     // words stats1
    stats1_body(P.words, P.wpart, 512, 640, 16, 7, bid - 4864, tid);
  }
}

__device__ __forceinline__ void stats2c_body(const MegaParams& P, int bid, int tid,
                                             char* shraw) {
  float4* sS = (float4*)shraw;
  float4* sQ = sS + 264;
  if (bid < 8) stats2_body(P.vpart, P.vms, 1024, 512, 1.f / 8192.f, bid, tid, sS, sQ);
  else         stats2_body(P.wpart, P.wms, 512,  80,  1.f / 640.f,  bid - 8, tid, sS, sQ);
}

// ---------------------------------------------------------------------------
// cast: video BN apply+cast (0..8191) | words BN->bf16 + Gram (8192..8223).
// Gram path stages BN'd sentence in LDS (float4 dots) — R9-verified; the
// R10-R12 global-scalar recompute was a 60us tail (cast_g top dispatch).
// ---------------------------------------------------------------------------
__device__ __forceinline__ void cast_body(const MegaParams& P, int w, int tid,
                                          float* sw /* 20*516 floats */) {
  if (w < 8192) {
    int i4 = w * 256 + tid;
    float4 v = reinterpret_cast<const float4*>(P.video)[i4];
    int c = (i4 & 255) * 4;
    v.x = (v.x - P.vms[c+0]) * P.vms[1024+c+0];
    v.y = (v.y - P.vms[c+1]) * P.vms[1024+c+1];
    v.z = (v.z - P.vms[c+2]) * P.vms[1024+c+2];
    v.w = (v.w - P.vms[c+3]) * P.vms[1024+c+3];
    ushort4_t h = { f2bf(v.x), f2bf(v.y), f2bf(v.z), f2bf(v.w) };
    reinterpret_cast<ushort4_t*>(P.vbf)[i4] = h;
  } else {
    int i = w - 8192;                        // sentence
    const float* wr = P.words + (size_t)i * L_ * DJ_;
    unsigned short* wb = P.wbnb + (size_t)i * L_ * DJ_;
    for (int idx = tid; idx < L_ * DJ_; idx += 256) {
      int l = idx >> 9, d = idx & 511;
      float x = (wr[idx] - P.wms[d]) * P.wms[DJ_ + d];
      sw[l * 516 + d] = x;
      wb[idx] = f2bf(x);
    }
    __syncthreads();
    for (int p = tid; p < L_ * L_; p += 256) {
      int l = p / L_, l2 = p % L_;
      const float4* a = reinterpret_cast<const float4*>(&sw[l * 516]);
      const float4* b = reinterpret_cast<const float4*>(&sw[l2 * 516]);
      float acc = 0.f;
      for (int d4 = 0; d4 < 128; ++d4) {
        float4 av = a[d4], bv = b[d4];
        acc += av.x*bv.x + av.y*bv.y + av.z*bv.z + av.w*bv.w;
      }
      P.G[i * 400 + p] = acc;
    }
  }
}

// ---------------------------------------------------------------------------
// MFMA bf16 GEMM stage.  [HW-verified R9/R10]
// ---------------------------------------------------------------------------
template<int BM, int BN, bool RELU, bool BIAS, bool OUT_BF16, bool PARTIAL, bool STATS>
__device__ __forceinline__ void gemm_stage(
    char* shraw, int lin, int gx, int gy, int gz,
    const unsigned short* __restrict__ xin, const unsigned short* __restrict__ Wr,
    const float* __restrict__ bias, void* __restrict__ out, float* __restrict__ spart,
    int b_stride, int row_off, int row_t_stride,
    int To, int M, int t_off_out, int ldout, int Ktot, int Kloc)
{
  constexpr int AI = BM / 64, BI = BN / 64;     // staging issues per side
  constexpr int FM = BM / 32, FN = BN / 32;     // frags per wave
  short* As   = (short*)shraw;                        // 2*BM*32 shorts
  short* Bs   = (short*)(shraw + (size_t)2 * BM * 32 * 2);
  float* wred = (float*)(shraw + 24576);

  const int tid  = threadIdx.x;
  const int lane = tid & 63;
  const int wv   = tid >> 6;
  const int wr   = wv >> 1;
  const int wc   = wv & 1;

  // bijective XCD swizzle (m204)
  const int nwg = gx * gy * gz;
  const int q = nwg >> 3, r = nwg & 7;
  const int xcd = lin & 7, sub = lin >> 3;
  const int work = (xcd < r ? xcd * (q + 1) : r * (q + 1) + (xcd - r) * q) + sub;
  const int bx = work % gx;
  const int by = (work / gx) % gy;
  const int bz = work / (gx * gy);

  const int mbase = bx * BM;
  const int nbase = by * BN;
  const int kstart = PARTIAL ? bz * Kloc : 0;

  const int srow = tid >> 2;                       // 0..63
  const int sb   = (((tid & 3) ^ ((srow ^ (srow >> 2)) & 3))) * 8;
  const unsigned short* agp[AI];
  const unsigned short* bgp[BI];
#pragma unroll
  for (int i = 0; i < AI; ++i) {
    int ma = min(mbase + i * 64 + srow, M - 1);
    int b0 = ma / To, t0 = ma % To;
    agp[i] = xin + (size_t)b0 * b_stride + row_off
             + (size_t)t0 * row_t_stride + sb + kstart;
  }
#pragma unroll
  for (int i = 0; i < BI; ++i)
    bgp[i] = Wr + (size_t)(nbase + i * 64 + srow) * Ktot + sb + kstart;

  f32x4 acc[FM][FN] = {};
  const int nsteps = Kloc >> 5;

#define STAGE_(buf, k0)                                                        \
  do {                                                                         \
    _Pragma("unroll")                                                          \
    for (int i = 0; i < AI; ++i)                                               \
      GLOAD_LDS16(agp[i] + (k0), &As[(buf) * (BM * 32) + i * 2048 + wv * 512]);\
    _Pragma("unroll")                                                          \
    for (int i = 0; i < BI; ++i)                                               \
      GLOAD_LDS16(bgp[i] + (k0), &Bs[(buf) * (BN * 32) + i * 2048 + wv * 512]);\
  } while (0)

  STAGE_(0, 0);
  __syncthreads();

  const int l15   = lane & 15;
  const int rsw   = (l15 ^ (l15 >> 2)) & 3;
  const int chunk = ((lane >> 4) ^ rsw) * 8;
  const int a_off = (wr * (BM / 2) + l15) * 32 + chunk;
  const int b_off = (wc * (BN / 2) + l15) * 32 + chunk;

  for (int s = 0; s < nsteps; ++s) {
    const int nb = s & 1;
    if (s + 1 < nsteps) STAGE_(nb ^ 1, (s + 1) * 32);

    const short* Ab = &As[nb * (BM * 32) + a_off];
    const short* Bb = &Bs[nb * (BN * 32) + b_off];
    short8 af[FM], bf[FN];
#pragma unroll
    for (int f = 0; f < FM; ++f)
      af[f] = *reinterpret_cast<const short8*>(Ab + f * 512);
#pragma unroll
    for (int f = 0; f < FN; ++f)
      bf[f] = *reinterpret_cast<const short8*>(Bb + f * 512);
#pragma unroll
    for (int fm = 0; fm < FM; ++fm)
#pragma unroll
      for (int fn = 0; fn < FN; ++fn)
        acc[fm][fn] = __builtin_amdgcn_mfma_f32_16x16x32_bf16(af[fm], bf[fn], acc[fm][fn], 0, 0, 0);

    __syncthreads();
  }
#undef STAGE_

  // epilogue: C/D map col=lane&15, row=4*(lane>>4)+reg
  const int cl = lane & 15, rh = lane >> 4;
  float ls[FN], lq[FN];
#pragma unroll
  for (int f = 0; f < FN; ++f) { ls[f] = 0.f; lq[f] = 0.f; }
#pragma unroll
  for (int fm = 0; fm < FM; ++fm) {
#pragma unroll
    for (int fn = 0; fn < FN; ++fn) {
      int col = nbase + wc * (BN / 2) + fn * 16 + cl;
      float bv = BIAS ? bias[col] : 0.f;
      f32x4 v = acc[fm][fn];
#pragma unroll
      for (int rr = 0; rr < 4; ++rr) {
        int m = mbase + wr * (BM / 2) + fm * 16 + rh * 4 + rr;
        if (m < M) {
          if (PARTIAL) {
            float* pout = (float*)out + (size_t)bz * ((size_t)M * ldout);
            pout[(size_t)m * ldout + col] = v[rr];
          } else {
            int b = m / To, to = m % To;
            float x = v[rr] + bv;
            if (RELU) x = fmaxf(x, 0.f);
            size_t oi = ((size_t)b * TP_ + t_off_out + to) * (size_t)ldout + col;
            if (OUT_BF16) ((unsigned short*)out)[oi] = f2bf(x);
            else          ((float*)out)[oi] = x;
            if (STATS) { ls[fn] += x; lq[fn] += x * x; }
          }
        }
      }
    }
  }

  if (STATS) {   // deterministic per-block column stats (BM=BN=64 path)
#pragma unroll
    for (int fn = 0; fn < FN; ++fn) {
      float s = ls[fn], qq = lq[fn];
      s  += __shfl_xor(s, 16, 64);  qq += __shfl_xor(qq, 16, 64);
      s  += __shfl_xor(s, 32, 64);  qq += __shfl_xor(qq, 32, 64);
      if (rh == 0) {
        wred[wv * 64 + fn * 16 + cl]      = s;
        wred[wv * 64 + 32 + fn * 16 + cl] = qq;
      }
    }
    __syncthreads();
    if (tid < 64) {
      int wc2 = tid >> 5, cl2 = tid & 31;
      float s  = wred[wc2 * 64 + cl2]      + wred[(wc2 + 2) * 64 + cl2];
      float qq = wred[wc2 * 64 + 32 + cl2] + wred[(wc2 + 2) * 64 + 32 + cl2];
      int chan = nbase + wc2 * 32 + cl2;
      spart[(size_t)bx * 1024 + chan]       = s;
      spart[(size_t)bx * 1024 + 512 + chan] = qq;
    }
    __syncthreads();
  }
}

// ---------------------------------------------------------------------------
// K-split reduce body
// ---------------------------------------------------------------------------
template<int S>
__device__ __forceinline__ void red_body(const float* __restrict__ part,
                                         const float* __restrict__ bias,
                                         unsigned short* __restrict__ outb,
                                         int M, int To, int t_off_out,
                                         int w, int tid) {
  int idx = w * 256 + tid;
  int m = idx >> 7, n4 = idx & 127;
  if (m >= M) return;
  size_t off = (size_t)m * 512 + n4 * 4;
  float4 a = *reinterpret_cast<const float4*>(part + off);
#pragma unroll
  for (int s = 1; s < S; ++s) {
    float4 b = *reinterpret_cast<const float4*>(part + (size_t)s * M * 512 + off);
    a.x += b.x; a.y += b.y; a.z += b.z; a.w += b.w;
  }
  float4 bv = *reinterpret_cast<const float4*>(bias + n4 * 4);
  a.x = fmaxf(a.x + bv.x, 0.f);
  a.y = fmaxf(a.y + bv.y, 0.f);
  a.z = fmaxf(a.z + bv.z, 0.f);
  a.w = fmaxf(a.w + bv.w, 0.f);
  int b_ = m / To, to = m % To;
  ushort4_t h = { f2bf(a.x), f2bf(a.y), f2bf(a.z), f2bf(a.w) };
  reinterpret_cast<ushort4_t*>(outb + ((size_t)b_ * TP_ + t_off_out + to) * 512)[n4] = h;
}

// ---------------------------------------------------------------------------
// v2 normalize + bf16 + row norm: 4 rows per 256-thread block
// ---------------------------------------------------------------------------
__device__ __forceinline__ void v2norm_body(const MegaParams& P, int w, int tid) {
  int r = w * 4 + (tid >> 6);
  int t = tid & 63;
  float* row = P.v2 + (size_t)r * DJ_;
  unsigned short* brow = P.v2bf + (size_t)r * DJ_;
  const float* ms = P.v2ms;
  float ss = 0.f;
#pragma unroll
  for (int h = 0; h < 2; ++h) {
    int c4 = t + h * 64;
    float4 v = reinterpret_cast<float4*>(row)[c4];
    int c = c4 * 4;
    v.x = (v.x - ms[c+0]) * ms[DJ_+c+0];
    v.y = (v.y - ms[c+1]) * ms[DJ_+c+1];
    v.z = (v.z - ms[c+2]) * ms[DJ_+c+2];
    v.w = (v.w - ms[c+3]) * ms[DJ_+c+3];
    reinterpret_cast<float4*>(row)[c4] = v;
    ushort4_t h4 = { f2bf(v.x), f2bf(v.y), f2bf(v.z), f2bf(v.w) };
    reinterpret_cast<ushort4_t*>(brow)[c4] = h4;
    ss += v.x*v.x + v.y*v.y + v.z*v.z + v.w*v.w;
  }
#pragma unroll
  for (int o = 32; o; o >>= 1) ss += __shfl_down(ss, o, 64);
  if (t == 0) P.vn[r] = sqrtf(ss);
}

// ---------------------------------------------------------------------------
// sim body (w = j + 32*i)
// ---------------------------------------------------------------------------
__device__ __forceinline__ void sim_body(const MegaParams& P, int w, int tid,
                                         char* shraw) {
  float* sG  = (float*)shraw;        // 400
  float* sm  = sG + 400;             // 20
  float* red = sm + 20;              // 4
  int j = w & 31, i = w >> 5;
  for (int p = tid; p < 400; p += 256) sG[p] = P.G[i * 400 + p];
  if (tid < 20) sm[tid] = P.wmask[i * 20 + tid];
  __syncthreads();

  float simv = -1e30f;
  if (tid < TP_) {
    const float* ar = P.Amat + ((size_t)j * TP_ + tid) * 640 + i * 20;
    float a[20], p[20];
    float mx = -1e30f;
#pragma unroll
    for (int l = 0; l < 20; ++l) {
      a[l] = ar[l];
      float lg = (sm[l] > 0.5f) ? LAM_ * a[l] : -1e9f;
      p[l] = lg;
      mx = fmaxf(mx, lg);
    }
    float Z = 0.f;
#pragma unroll
    for (int l = 0; l < 20; ++l) { p[l] = __expf(p[l] - mx); Z += p[l]; }
    float invZ = 1.f / Z, num = 0.f;
#pragma unroll
    for (int l = 0; l < 20; ++l) { p[l] *= invZ; num += p[l] * a[l]; }
    float q2 = 0.f;
#pragma unroll
    for (int l = 0; l < 20; ++l) {
      float gi = 0.f;
#pragma unroll
      for (int l2 = 0; l2 < 20; ++l2) gi += sG[l * 20 + l2] * p[l2];
      q2 += p[l] * gi;
    }
    float vnv = fmaxf(P.vn[(size_t)j * TP_ + tid], 1e-8f);
    float vsnv = fmaxf(sqrtf(q2), 1e-8f);
    simv = num / (vnv * vsnv);
    if (i == j) P.out[1 + i * TP_ + tid] = simv;
  }
  float mv = simv;
#pragma unroll
  for (int o = 32; o; o >>= 1) mv = fmaxf(mv, __shfl_down(mv, o, 64));
  if ((tid & 63) == 0) red[tid >> 6] = mv;
  __syncthreads();
  if (tid == 0)
    P.scores[i * 32 + j] = fmaxf(fmaxf(red[0], red[1]), fmaxf(red[2], red[3]));
}

// loss over scores[32][32] with 256 threads
__device__ __forceinline__ void loss_body(const MegaParams& P, int tid, char* shraw) {
  float* red = (float*)shraw;
  const float* s = P.scores;
  float c = 0.f;
  for (int p = tid; p < 1024; p += 256) {
    int i = p >> 5, j = p & 31;
    float sv = s[p];
    if (i != j)
      c += fmaxf(0.f, MARGIN_ + sv - s[i * 32 + i]) +
           fmaxf(0.f, MARGIN_ + sv - s[j * 32 + j]);
  }
#pragma unroll
  for (int o = 32; o; o >>= 1) c += __shfl_down(c, o, 64);
  if ((tid & 63) == 0) red[tid >> 6] = c;
  __syncthreads();
  if (tid == 0) P.out[0] = (red[0] + red[1] + red[2] + red[3]) / 32.f;
}

// ---------------------------------------------------------------------------
// Kernels (15-launch pipeline, R9 structure)
// ---------------------------------------------------------------------------
__global__ __launch_bounds__(256) void prep_g(MegaParams P) {
  prep_body(P, blockIdx.x, threadIdx.x);
}
__global__ __launch_bounds__(256) void stats2c_g(MegaParams P) {
  __shared__ __align__(16) char shraw[8448];
  stats2c_body(P, blockIdx.x, threadIdx.x, shraw);
}
__global__ __launch_bounds__(256) void cast_g(MegaParams P) {
  __shared__ __align__(16) float sw[L_ * 516];   // 41.3 KB (Gram blocks only)
  cast_body(P, blockIdx.x, threadIdx.x, sw);
}
template<int BM, int BN, bool RELU, bool BIAS, bool OUT_BF16, bool PARTIAL, bool STATS>
__global__ __launch_bounds__(256) void gemm_g(
    const unsigned short* xin, const unsigned short* Wr, const float* bias,
    void* out, float* spart, int b_stride, int row_off, int row_t_stride,
    int To, int M, int t_off_out, int ldout, int Ktot, int Kloc) {
  __shared__ __align__(16) char shraw[SHBYTES];
  int lin = blockIdx.x + gridDim.x * (blockIdx.y + gridDim.y * blockIdx.z);
  gemm_stage<BM,BN,RELU,BIAS,OUT_BF16,PARTIAL,STATS>(
      shraw, lin, gridDim.x, gridDim.y, gridDim.z, xin, Wr, bias, out, spart,
      b_stride, row_off, row_t_stride, To, M, t_off_out, ldout, Ktot, Kloc);
}
template<int S>
__global__ __launch_bounds__(256) void red_g(const float* part, const float* bias,
                                             unsigned short* outb,
                                             int M, int To, int t_off_out) {
  red_body<S>(part, bias, outb, M, To, t_off_out, blockIdx.x, threadIdx.x);
}
__global__ __launch_bounds__(256) void stats2v_g(MegaParams P) {
  __shared__ __align__(16) char shraw[8448];
  stats2_body(P.v2part, P.v2ms, 512, 110, 1.f / 7008.f, blockIdx.x, threadIdx.x,
              (float4*)shraw, (float4*)shraw + 264);
}
__global__ __launch_bounds__(256) void v2norm_g(MegaParams P) {
  v2norm_body(P, blockIdx.x, threadIdx.x);
}
__global__ __launch_bounds__(256) void sim_g(MegaParams P) {
  __shared__ __align__(16) char shraw[1696];
  sim_body(P, blockIdx.x, threadIdx.x, shraw);
}
__global__ __launch_bounds__(256) void loss_g(MegaParams P) {
  __shared__ __align__(16) char shraw[64];
  loss_body(P, threadIdx.x, shraw);
}

// ---------------------------------------------------------------------------
extern "C" void kernel_launch(void* const* d_in, const int* in_sizes, int n_in,
                              void* d_out, int out_size, void* d_ws, size_t ws_size,
                              hipStream_t stream) {
  float* ws = (float*)d_ws;

  // ---- workspace layout (float units); R9 layout ----
  float*          W0r    = ws;                       // 1048576
  float*          W1r    = W0r + 1048576;            // 524288
  float*          W2r    = W1r + 524288;             // 524288
  float*          Wpw    = W2r + 524288;             // 131072
  float*          AMvbf  = Wpw + 131072;             // 4485120 (vbf | Amat)
  float*          vcatb  = AMvbf + 4485120;          // 1794048 (bf16 vcat)
  float*          Pbuf   = vcatb + 1794048;          // 8323072 overlay:
  float*          v2     = Pbuf;                     //   3588096
  float*          v2bfp  = v2 + 3588096;             //   1794048
  float*          v2part = v2bfp + 1794048;          //   112640
  float*          v2ms   = v2part + 112640;          //   1024
  float*          vpart  = v2ms + 1024;              //   1048576
  float*          vms    = vpart + 1048576;          //   2048
  float*          wpart  = vms + 2048;               //   81920
  float*          wms    = wpart + 81920;            //   1024 (fits 8323072)
  float*          endPb  = Pbuf + 8323072;
  float*          wbnbp  = endPb;                    // 163840 (bf16 327680)
  float*          G      = wbnbp + 163840;           // 12800
  float*          vn     = G + 12800;                // 7008
  float*          scores = vn + 7008;                // 1024

  MegaParams P;
  P.video = (const float*)d_in[0];
  P.words = (const float*)d_in[1];
  P.wmask = (const float*)d_in[2];
  P.c0w = (const float*)d_in[3];  P.c0b = (const float*)d_in[4];
  P.c1w = (const float*)d_in[5];  P.c1b = (const float*)d_in[6];
  P.c2w = (const float*)d_in[7];  P.c2b = (const float*)d_in[8];
  P.pww = (const float*)d_in[9];  P.pwb = (const float*)d_in[10];
  P.out = (float*)d_out;
  P.W0 = (unsigned short*)W0r;  P.W1 = (unsigned short*)W1r;
  P.W2 = (unsigned short*)W2r;  P.Wp = (unsigned short*)Wpw;
  P.vbf = (unsigned short*)AMvbf;
  P.vcb = (unsigned short*)vcatb;
  P.v2bf = (unsigned short*)v2bfp;
  P.wbnb = (unsigned short*)wbnbp;
  P.Amat = AMvbf;   P.Pbuf = Pbuf;   P.v2 = v2;
  P.v2part = v2part; P.v2ms = v2ms;  P.vpart = vpart; P.vms = vms;
  P.wpart = wpart;  P.wms = wms;     P.G = G; P.vn = vn; P.scores = scores;

  // 1: weight reorder + video/words stats1
  prep_g<<<4904, 256, 0, stream>>>(P);
  // 2: video + words stats2
  stats2c_g<<<12, 256, 0, stream>>>(P);
  // 3: video BN cast + words BN->bf16 + Gram (LDS-staged)
  cast_g<<<8224, 256, 0, stream>>>(P);
  // 4/5: conv0 (64x128, K 4x1024) + reduce
  gemm_g<64,128,false,false,false,true,false><<<dim3(64, 4, 4), 256, 0, stream>>>(
      P.vbf, P.W0, nullptr, P.Pbuf, nullptr, 262144, 0, 2048, T0_, 32 * T0_, 0, 512, 4096, 1024);
  red_g<4><<<2032, 256, 0, stream>>>(P.Pbuf, P.c0b, P.vcb, 32 * T0_, T0_, 0);
  // 6/7: conv1 (64x128, K 8x256) + reduce
  gemm_g<64,128,false,false,false,true,false><<<dim3(31, 4, 8), 256, 0, stream>>>(
      P.vcb, P.W1, nullptr, P.Pbuf, nullptr, 112128, 0, 1024, T1_, 32 * T1_, 0, 512, 2048, 256);
  red_g<8><<<992, 256, 0, stream>>>(P.Pbuf, P.c1b, P.vcb, 32 * T1_, T1_, T0_);
  // 8/9: conv2 (64x64, K 8x256) + reduce
  gemm_g<64,64,false,false,false,true,false><<<dim3(15, 8, 8), 256, 0, stream>>>(
      P.vcb, P.W2, nullptr, P.Pbuf, nullptr, 112128, 65024, 1024, T2_, 32 * T2_, 0, 512, 2048, 256);
  red_g<8><<<480, 256, 0, stream>>>(P.Pbuf, P.c2b, P.vcb, 32 * T2_, T2_, T0_ + T1_);
  // 10: pointwise conv + fused stats1 epilogue
  gemm_g<64,64,false,true,false,false,true><<<dim3(110, 8), 256, 0, stream>>>(
      P.vcb, P.Wp, P.pwb, P.v2, P.v2part, 112128, 0, 512, TP_, 32 * TP_, 0, 512, 512, 512);
  // 11: v2 stats2
  stats2v_g<<<4, 256, 0, stream>>>(P);
  // 12: v2 BN apply + bf16 + row norms
  v2norm_g<<<1752, 256, 0, stream>>>(P);
  // 13: attention A = v.w  (M=7008, N=640, K=512)
  gemm_g<64,64,false,false,false,false,false><<<dim3(110, 10), 256, 0, stream>>>(
      P.v2bf, P.wbnb, nullptr, P.Amat, nullptr, 112128, 0, 512, TP_, 32 * TP_, 0, 640, 512, 512);
  // 14: sim / scores / positive map
  sim_g<<<1024, 256, 0, stream>>>(P);
  // 15: loss
  loss_g<<<1, 256, 0, stream>>>(P);
}